// Round 5
// baseline (338.124 us; speedup 1.0000x reference)
//
#include <hip/hip_runtime.h>
#include <math.h>

#define EPSF 1e-5f
#define MAXNF (1.0f - 1e-5f)

constexpr int SEGc = 24;
constexpr int Nn   = 14;          // L / SEG
constexpr int NS   = Nn * SEGc;   // 336
constexpr int Tt   = 4;           // horizons
constexpr int Bb   = 32;
constexpr int Ll   = 336;
constexpr int Ff   = 256;
constexpr int Dd   = 128;
constexpr int Hh   = 256;
constexpr int BFc  = Bb * Ff;     // 8192

// logmap mean weights: WJT[j-1] = 0.9^(13-j) / (sum_{i=0}^{12}0.9^i * 13)
constexpr float WNORM = 1.0f / (7.458134171670999f * 13.0f);
constexpr float WJT[13] = {
    0.28242953648100017f * WNORM, 0.3138105960900002f  * WNORM,
    0.34867844010000015f * WNORM, 0.38742048900000015f * WNORM,
    0.4304672100000001f  * WNORM, 0.47829690000000014f * WNORM,
    0.5314410000000002f  * WNORM, 0.5904900000000001f  * WNORM,
    0.6561f * WNORM, 0.729f * WNORM, 0.81f * WNORM, 0.9f * WNORM,
    1.0f * WNORM};

// ---- fast math (tolerance 1.8e-2; these are ~1e-7 relative) ----
__device__ __forceinline__ float frcp(float x)  { return __builtin_amdgcn_rcpf(x); }
__device__ __forceinline__ float fsqrtf_(float x){ return __builtin_amdgcn_sqrtf(x); }
__device__ __forceinline__ float ftanh_pos(float x) {       // x >= 0
    const float e = __expf(fminf(2.f * x, 30.f));           // v_exp_f32
    return (e - 1.f) * frcp(e + 1.f);
}
__device__ __forceinline__ float fatanh01(float x) {        // 0 <= x <= MAXNF
    return 0.5f * __logf((1.f + x) * frcp(1.f - x));        // v_log_f32
}

// ---- DPP wave-sum: pure VALU, result uniform (readlane 63) ----
#define DPPADD(v, ctrl, rmask)                                                \
    v += __int_as_float(__builtin_amdgcn_update_dpp(                          \
        0, __float_as_int(v), (ctrl), (rmask), 0xF, false))

__device__ __forceinline__ float wredsum(float v) {
    DPPADD(v, 0xB1, 0xF);    // quad_perm [1,0,3,2]  (xor1)
    DPPADD(v, 0x4E, 0xF);    // quad_perm [2,3,0,1]  (xor2)
    DPPADD(v, 0x141, 0xF);   // row_half_mirror      (xor within 8)
    DPPADD(v, 0x140, 0xF);   // row_mirror           (within 16)
    DPPADD(v, 0x142, 0xA);   // row_bcast15 -> rows 1,3
    DPPADD(v, 0x143, 0xC);   // row_bcast31 -> rows 2,3
    return __int_as_float(
        __builtin_amdgcn_readlane(__float_as_int(v), 63));
}

// ---------------- fused kernel: one block (4 waves) per bf ----------------
// wave wid = component c during branch phase, = horizon t during fusion.
// lane owns dims d0=2*lane, d1=2*lane+1.
__global__ __launch_bounds__(256) void fused_kernel(
    const float* __restrict__ trend, const float* __restrict__ scoarse,
    const float* __restrict__ sfine, const float* __restrict__ resid,
    const float* __restrict__ revin_w, const float* __restrict__ revin_b,
    const float* __restrict__ enc_W, const float* __restrict__ enc_b,
    const float* __restrict__ vel_W, const float* __restrict__ vel_b,
    const float* __restrict__ steps, const float* __restrict__ mobius_w,
    const float* __restrict__ rec_W1, const float* __restrict__ rec_b1,
    const float* __restrict__ rec_W2, const float* __restrict__ rec_b2,
    float* __restrict__ out, float* __restrict__ hpart)
{
    const int bf   = blockIdx.x;
    const int b    = bf >> 8;
    const int f    = bf & 255;
    const int tid  = threadIdx.x;
    const int wid  = tid >> 6;     // 0..3
    const int lane = tid & 63;

    __shared__ float xs[4 * NS];       // RAW comp rows; later reused as hbuf[4*Hh]
    __shared__ float bcu[4 * Dd];      // per-comp bc (branch), then per-horizon uls
    __shared__ float zfl[4][Tt][Dd];   // z_fut
    __shared__ float zfns[4][Tt];      // clipped norms
    __shared__ float red[8];

    const float* cp = (wid == 0) ? trend : (wid == 1) ? scoarse
                    : (wid == 2) ? sfine : resid;

    // ---- stage raw component rows (each wave its component) ----
    for (int i = lane; i < NS; i += 64)
        xs[wid * NS + i] = cp[(b * Ll + i) * Ff + f];
    __syncthreads();

    // ---- RevIN stats on combined signal ----
    float sum = 0.f, sumsq = 0.f;
    for (int l = tid; l < NS; l += 256) {
        const float x = xs[l] + xs[NS + l] + xs[2 * NS + l] + xs[3 * NS + l];
        sum += x; sumsq += x * x;
    }
    sum = wredsum(sum); sumsq = wredsum(sumsq);
    if (lane == 0) { red[wid] = sum; red[4 + wid] = sumsq; }
    __syncthreads();
    sum   = red[0] + red[1] + red[2] + red[3];
    sumsq = red[4] + red[5] + red[6] + red[7];
    const float mean    = sum * (1.f / (float)NS);
    const float stdv    = fsqrtf_(sumsq * (1.f / (float)NS) - mean * mean + 1e-5f);
    const float inv_std = frcp(stdv);
    const float rw = revin_w[f], rb = revin_b[f];
    // affine fold: scaled = raw * a_aff + k_aff
    const float a_aff = inv_std * rw;
    const float k_aff = 0.25f * (rb - mean * a_aff);

    // ================= branch (component c = wid) =================
    const int c = wid;
    const float4* xv4 = reinterpret_cast<const float4*>(xs + c * NS);
    const float* Wep  = enc_W + c * SEGc * Dd + 2 * lane;
    const float* Wvp  = vel_W + c * Dd * Dd + 2 * lane;

    float2 wreg[SEGc];
#pragma unroll
    for (int s = 0; s < SEGc; ++s)
        wreg[s] = *reinterpret_cast<const float2*>(Wep + s * Dd);
    const float2 be = *reinterpret_cast<const float2*>(enc_b + c * Dd + 2 * lane);
    const float2 bv = *reinterpret_cast<const float2*>(vel_b + c * Dd + 2 * lane);

    // column sums for the affine fold
    float cs0 = 0.f, cs1 = 0.f;
#pragma unroll
    for (int s = 0; s < SEGc; ++s) { cs0 += wreg[s].x; cs1 += wreg[s].y; }
    const float kb0 = fmaf(k_aff, cs0, be.x);
    const float kb1 = fmaf(k_aff, cs1, be.y);

    // --- Phase A: all 14 encoder dots on RAW data (independent) ---
    float y0[Nn], y1[Nn], qn[Nn];
#pragma unroll
    for (int n = 0; n < Nn; ++n) {
        float a = 0.f, d = 0.f;
#pragma unroll
        for (int q = 0; q < SEGc / 4; ++q) {
            const float4 xv = xv4[n * (SEGc / 4) + q];
            a = fmaf(xv.x, wreg[4*q+0].x, a); d = fmaf(xv.x, wreg[4*q+0].y, d);
            a = fmaf(xv.y, wreg[4*q+1].x, a); d = fmaf(xv.y, wreg[4*q+1].y, d);
            a = fmaf(xv.z, wreg[4*q+2].x, a); d = fmaf(xv.z, wreg[4*q+2].y, d);
            a = fmaf(xv.w, wreg[4*q+3].x, a); d = fmaf(xv.w, wreg[4*q+3].y, d);
        }
        a = fmaf(a_aff, a, kb0); d = fmaf(a_aff, d, kb1);
        y0[n] = a; y1[n] = d; qn[n] = a * a + d * d;
    }
    // --- 14 independent DPP reductions (VALU-only, pipelined) ---
#pragma unroll
    for (int n = 0; n < Nn; ++n) qn[n] = wredsum(qn[n]);
    // --- per-n scalars (independent): scale + norm2 ---
    float sc[Nn], zn2a[Nn];
#pragma unroll
    for (int n = 0; n < Nn; ++n) {
        const float vn = fsqrtf_(fmaxf(qn[n], EPSF * EPSF));
        const float th = ftanh_pos(vn);
        float s = th * frcp(vn);
        float nrm = th;
        if (nrm > MAXNF) { s *= MAXNF * frcp(nrm); nrm = MAXNF; }
        sc[n] = s; zn2a[n] = nrm * nrm;
    }
    // --- neighbor dots y_{n-1}.y_n, 13 independent DPP reductions ---
    float rd[Nn - 1];
#pragma unroll
    for (int n = 1; n < Nn; ++n)
        rd[n - 1] = y0[n - 1] * y0[n] + y1[n - 1] * y1[n];
#pragma unroll
    for (int j = 0; j < Nn - 1; ++j) rd[j] = wredsum(rd[j]);
    // --- logmap chain, all scalar (analytic |u|^2), independent across j ---
    float coef[Nn];
#pragma unroll
    for (int n = 0; n < Nn; ++n) coef[n] = 0.f;
#pragma unroll
    for (int j = 1; j < Nn; ++j) {
        const float xy  = -(sc[j-1] * sc[j] * rd[j-1]);
        const float x2  = zn2a[j-1], yy2 = zn2a[j];
        const float c1  = 1.f + 2.f * xy + yy2;
        const float c2  = 1.f - x2;
        const float rden = frcp(fmaxf(1.f + 2.f * xy + x2 * yy2, EPSF));
        const float un2 = rden * rden *
            (c1 * c1 * x2 + 2.f * c1 * c2 * xy + c2 * c2 * yy2);
        const float un  = fsqrtf_(fmaxf(un2, EPSF * EPSF));
        const float lf  = fmaxf(1.f - x2, EPSF);            // 2/lam
        const float g   = lf * fatanh01(fminf(un, MAXNF)) * frcp(un);
        const float gw  = WJT[j-1] * g * rden;
        coef[j-1] = fmaf(-gw * c1, sc[j-1], coef[j-1]);
        coef[j]   = fmaf( gw * c2, sc[j],   coef[j]);
    }
    float vi0 = 0.f, vi1 = 0.f;
#pragma unroll
    for (int n = 0; n < Nn; ++n) {
        vi0 = fmaf(coef[n], y0[n], vi0);
        vi1 = fmaf(coef[n], y1[n], vi1);
    }
    const float z0l = y0[Nn-1] * sc[Nn-1], z1l = y1[Nn-1] * sc[Nn-1];
    const float x2l = zn2a[Nn-1];

    // --- v0t = projx(expmap0(logmap0(v_init) @ Wv + bv)) ---
    const float vin2 = wredsum(vi0 * vi0 + vi1 * vi1);
    const float vin  = fsqrtf_(fmaxf(vin2, EPSF * EPSF));
    const float lgv  = fatanh01(fminf(vin, MAXNF)) * frcp(vin);
    float* bc = bcu + c * Dd;
    *reinterpret_cast<float2*>(bc + 2 * lane) = make_float2(lgv * vi0, lgv * vi1);
    __syncthreads();

    float m0 = bv.x, m1 = bv.y;
    {
        const float4* bc4 = reinterpret_cast<const float4*>(bc);
#pragma unroll 4
        for (int kb = 0; kb < Dd / 8; ++kb) {      // 8-deep load batches
            float2 w[8];
#pragma unroll
            for (int r = 0; r < 8; ++r)
                w[r] = *reinterpret_cast<const float2*>(Wvp + (8*kb+r) * Dd);
            const float4 ta = bc4[2*kb], tb = bc4[2*kb+1];
            m0 = fmaf(ta.x, w[0].x, m0); m1 = fmaf(ta.x, w[0].y, m1);
            m0 = fmaf(ta.y, w[1].x, m0); m1 = fmaf(ta.y, w[1].y, m1);
            m0 = fmaf(ta.z, w[2].x, m0); m1 = fmaf(ta.z, w[2].y, m1);
            m0 = fmaf(ta.w, w[3].x, m0); m1 = fmaf(ta.w, w[3].y, m1);
            m0 = fmaf(tb.x, w[4].x, m0); m1 = fmaf(tb.x, w[4].y, m1);
            m0 = fmaf(tb.y, w[5].x, m0); m1 = fmaf(tb.y, w[5].y, m1);
            m0 = fmaf(tb.z, w[6].x, m0); m1 = fmaf(tb.z, w[6].y, m1);
            m0 = fmaf(tb.w, w[7].x, m0); m1 = fmaf(tb.w, w[7].y, m1);
        }
    }
    const float mn2 = wredsum(m0 * m0 + m1 * m1);
    const float zdm = wredsum(z0l * m0 + z1l * m1);
    const float mn  = fsqrtf_(fmaxf(mn2, EPSF * EPSF));
    const float th2 = ftanh_pos(mn);
    float sc2 = th2 * frcp(mn);
    float v0n = th2;
    if (v0n > MAXNF) { sc2 *= MAXNF * frcp(v0n); v0n = MAXNF; }
    const float v00 = m0 * sc2, v01 = m1 * sc2;
    const float v0n2 = mn2 * sc2 * sc2;
    const float zdotv = sc2 * zdm;

    const float lamx = 2.f * frcp(fmaxf(1.f - x2l, EPSF));
    const float sig  = frcp(1.f + __expf(-steps[c]));

#pragma unroll
    for (int t = 0; t < Tt; ++t) {
        const float alpha = sig * (float)(t + 1);
        const float vtn2  = alpha * alpha * v0n2;
        const float vtn   = fsqrtf_(fmaxf(vtn2, EPSF * EPSF));
        const float g     = ftanh_pos(0.5f * lamx * vtn);
        const float cyc   = g * alpha * frcp(vtn);     // y = cyc * v0t
        const float y2    = cyc * cyc * v0n2;
        const float xy    = cyc * zdotv;
        const float c1 = 1.f + 2.f * xy + y2;
        const float c2 = 1.f - x2l;
        const float rden = frcp(fmaxf(1.f + 2.f * xy + x2l * y2, EPSF));
        float rn2 = rden * rden *
            (c1 * c1 * x2l + 2.f * c1 * c2 * xy + c2 * c2 * y2);
        float r0 = (c1 * z0l + c2 * cyc * v00) * rden;
        float r1 = (c1 * z1l + c2 * cyc * v01) * rden;
        float rn = fsqrtf_(fmaxf(rn2, EPSF * EPSF));
        if (rn > MAXNF) { const float s = MAXNF * frcp(rn); r0 *= s; r1 *= s; rn = MAXNF; }
        *reinterpret_cast<float2*>(&zfl[c][t][2 * lane]) = make_float2(r0, r1);
        if (lane == 0) zfns[c][t] = rn;
    }
    __syncthreads();

    // ======= Mobius fusion via Gram matrix: wave wid = horizon t =======
    {
        float mw0 = mobius_w[0], mw1 = mobius_w[1], mw2 = mobius_w[2], mw3 = mobius_w[3];
        const float mx = fmaxf(fmaxf(mw0, mw1), fmaxf(mw2, mw3));
        mw0 = __expf(mw0 - mx); mw1 = __expf(mw1 - mx);
        mw2 = __expf(mw2 - mx); mw3 = __expf(mw3 - mx);
        const float rse = frcp(mw0 + mw1 + mw2 + mw3);
        const float mwv[4] = {mw0 * rse, mw1 * rse, mw2 * rse, mw3 * rse};

        const int t = wid;
        float2 e[4];
#pragma unroll
        for (int i = 0; i < 4; ++i)
            e[i] = *reinterpret_cast<const float2*>(&zfl[i][t][2 * lane]);

        float gp[6];
        gp[0] = e[0].x * e[1].x + e[0].y * e[1].y;   // G01
        gp[1] = e[0].x * e[2].x + e[0].y * e[2].y;   // G02
        gp[2] = e[0].x * e[3].x + e[0].y * e[3].y;   // G03
        gp[3] = e[1].x * e[2].x + e[1].y * e[2].y;   // G12
        gp[4] = e[1].x * e[3].x + e[1].y * e[3].y;   // G13
        gp[5] = e[2].x * e[3].x + e[2].y * e[3].y;   // G23
#pragma unroll
        for (int k = 0; k < 6; ++k) gp[k] = wredsum(gp[k]);

        const float xn[4] = {zfns[0][t], zfns[1][t], zfns[2][t], zfns[3][t]};
        const float Gd[4] = {xn[0]*xn[0], xn[1]*xn[1], xn[2]*xn[2], xn[3]*xn[3]};
        const float G[4][4] = {
            {Gd[0], gp[0], gp[1], gp[2]},
            {gp[0], Gd[1], gp[3], gp[4]},
            {gp[1], gp[3], Gd[2], gp[5]},
            {gp[2], gp[4], gp[5], Gd[3]}};
        float sm[4];
#pragma unroll
        for (int i = 0; i < 4; ++i)
            sm[i] = ftanh_pos(mwv[i] * fatanh01(xn[i])) * frcp(xn[i]);

        float a0 = sm[0], a1 = 0.f, a2 = 0.f, a3 = 0.f;
        float cn2 = sm[0] * sm[0] * Gd[0];
#pragma unroll
        for (int i = 1; i < 4; ++i) {
            const float si = sm[i];
            const float xy = si * (a0 * G[0][i] + a1 * G[1][i] + a2 * G[2][i] + a3 * G[3][i]);
            const float y2 = si * si * Gd[i];
            const float c1 = 1.f + 2.f * xy + y2;
            const float c2 = 1.f - cn2;
            const float rden = frcp(fmaxf(1.f + 2.f * xy + cn2 * y2, EPSF));
            const float f1 = rden * c1, f2 = rden * c2 * si;
            a0 *= f1; a1 *= f1; a2 *= f1; a3 *= f1;
            if (i == 1) a1 += f2; else if (i == 2) a2 += f2; else a3 += f2;
            cn2 = rden * rden * (c1 * c1 * cn2 + 2.f * c1 * c2 * xy + c2 * c2 * y2);
        }
        float cn = fsqrtf_(fmaxf(cn2, EPSF * EPSF));
        float csc = 1.f;
        if (cn > MAXNF) { csc = MAXNF * frcp(cn); cn = MAXNF; }
        const float lg = fatanh01(cn) * frcp(cn) * csc;
        const float u0 = lg * (a0 * e[0].x + a1 * e[1].x + a2 * e[2].x + a3 * e[3].x);
        const float u1 = lg * (a0 * e[0].y + a1 * e[1].y + a2 * e[2].y + a3 * e[3].y);
        *reinterpret_cast<float2*>(&bcu[t * Dd + 2 * lane]) = make_float2(u0, u1);
    }

    // ---- hinge-loss partial (wave 0) ----
    if (wid == 0) {
        float ddv = 0.f;
        if (lane < 16)
            ddv = 2.f * fatanh01(zfns[lane & 3][lane >> 2]);
        const float ddn = __shfl(ddv, lane + 1, 64);      // next comp, same t
        float hv = ((lane < 16) && ((lane & 3) != 3))
                 ? fmaxf(ddv - ddn + 0.1f, 0.f) : 0.f;
        hv = wredsum(hv);
        if (lane == 0) hpart[bf] = hv;
    }
    __syncthreads();

    // ---- reconstruction head, all 256 threads: h[t][j], j = tid ----
    {
        const float4* u4 = reinterpret_cast<const float4*>(bcu);
        float a0 = rec_b1[tid], a1 = a0, a2 = a0, a3 = a0;
        const float* w1p = rec_W1 + tid;
#pragma unroll 4
        for (int kb = 0; kb < Dd / 8; ++kb) {      // 8-deep load batches
            float wv[8];
#pragma unroll
            for (int r = 0; r < 8; ++r) wv[r] = w1p[(8*kb+r) * Hh];
#pragma unroll
            for (int r2 = 0; r2 < 2; ++r2) {
                const float4 u0 = u4[0 * (Dd/4) + 2*kb + r2];
                const float4 u1 = u4[1 * (Dd/4) + 2*kb + r2];
                const float4 u2 = u4[2 * (Dd/4) + 2*kb + r2];
                const float4 u3 = u4[3 * (Dd/4) + 2*kb + r2];
                const float wa = wv[4*r2+0], wb = wv[4*r2+1];
                const float wc = wv[4*r2+2], wd = wv[4*r2+3];
                a0 = fmaf(u0.x, wa, a0); a0 = fmaf(u0.y, wb, a0);
                a0 = fmaf(u0.z, wc, a0); a0 = fmaf(u0.w, wd, a0);
                a1 = fmaf(u1.x, wa, a1); a1 = fmaf(u1.y, wb, a1);
                a1 = fmaf(u1.z, wc, a1); a1 = fmaf(u1.w, wd, a1);
                a2 = fmaf(u2.x, wa, a2); a2 = fmaf(u2.y, wb, a2);
                a2 = fmaf(u2.z, wc, a2); a2 = fmaf(u2.w, wd, a2);
                a3 = fmaf(u3.x, wa, a3); a3 = fmaf(u3.y, wb, a3);
                a3 = fmaf(u3.z, wc, a3); a3 = fmaf(u3.w, wd, a3);
            }
        }
        xs[0 * Hh + tid] = fmaxf(a0, 0.f);
        xs[1 * Hh + tid] = fmaxf(a1, 0.f);
        xs[2 * Hh + tid] = fmaxf(a2, 0.f);
        xs[3 * Hh + tid] = fmaxf(a3, 0.f);
    }
    __syncthreads();

    // ---- seg outputs: 96 of them, threads 0..95 ----
    if (tid < Tt * SEGc) {
        const int t = tid / SEGc, s = tid - t * SEGc;
        const float4* h4 = reinterpret_cast<const float4*>(xs + t * Hh);
        const float* w2p = rec_W2 + s;
        float acc = rec_b2[s];
#pragma unroll 8
        for (int jb = 0; jb < Hh / 8; ++jb) {
            float wv[8];
#pragma unroll
            for (int r = 0; r < 8; ++r) wv[r] = w2p[(8*jb+r) * SEGc];
            const float4 ha = h4[2*jb], hb = h4[2*jb+1];
            acc = fmaf(ha.x, wv[0], acc); acc = fmaf(ha.y, wv[1], acc);
            acc = fmaf(ha.z, wv[2], acc); acc = fmaf(ha.w, wv[3], acc);
            acc = fmaf(hb.x, wv[4], acc); acc = fmaf(hb.y, wv[5], acc);
            acc = fmaf(hb.z, wv[6], acc); acc = fmaf(hb.w, wv[7], acc);
        }
        const float val = (acc - rb) * frcp(rw) * stdv + mean;   // RevIN denorm
        out[(b * (Tt * SEGc) + tid) * Ff + f] = val;
    }
}

// ---------------- deterministic hloss reduction ----------------
__global__ __launch_bounds__(256) void hloss_kernel(
    const float* __restrict__ hpart, float* __restrict__ out)
{
    __shared__ float sm[256];
    const int tid = threadIdx.x;
    float s = 0.f;
    for (int i = tid; i < BFc; i += 256) s += hpart[i];
    sm[tid] = s;
    __syncthreads();
    for (int off = 128; off > 0; off >>= 1) {
        if (tid < off) sm[tid] += sm[tid + off];
        __syncthreads();
    }
    if (tid == 0) out[Bb * Tt * SEGc * Ff] = sm[0] / (float)(BFc * Tt);
}

extern "C" void kernel_launch(void* const* d_in, const int* in_sizes, int n_in,
                              void* d_out, int out_size, void* d_ws, size_t ws_size,
                              hipStream_t stream) {
    const float* trend   = (const float*)d_in[0];
    const float* scoarse = (const float*)d_in[1];
    const float* sfine   = (const float*)d_in[2];
    const float* resid   = (const float*)d_in[3];
    const float* revin_w = (const float*)d_in[4];
    const float* revin_b = (const float*)d_in[5];
    const float* enc_W   = (const float*)d_in[6];
    const float* enc_b   = (const float*)d_in[7];
    const float* vel_W   = (const float*)d_in[8];
    const float* vel_b   = (const float*)d_in[9];
    const float* steps   = (const float*)d_in[10];
    const float* mobw    = (const float*)d_in[11];
    const float* rec_W1  = (const float*)d_in[12];
    const float* rec_b1  = (const float*)d_in[13];
    const float* rec_W2  = (const float*)d_in[14];
    const float* rec_b2  = (const float*)d_in[15];

    float* out = (float*)d_out;
    float* wsf = (float*)d_ws;           // hpart[8192]

    fused_kernel<<<BFc, 256, 0, stream>>>(
        trend, scoarse, sfine, resid, revin_w, revin_b,
        enc_W, enc_b, vel_W, vel_b, steps, mobw,
        rec_W1, rec_b1, rec_W2, rec_b2,
        out, wsf);
    hloss_kernel<<<1, 256, 0, stream>>>(wsf, out);
}

// Round 6
// 282.710 us; speedup vs baseline: 1.1960x; 1.1960x over previous
//
#include <hip/hip_runtime.h>
#include <math.h>

#define EPSF 1e-5f
#define MAXNF (1.0f - 1e-5f)

constexpr int SEGc = 24;
constexpr int Nn   = 14;          // L / SEG
constexpr int NS   = Nn * SEGc;   // 336
constexpr int Tt   = 4;           // horizons
constexpr int Bb   = 32;
constexpr int Ll   = 336;
constexpr int Ff   = 256;
constexpr int Dd   = 128;
constexpr int Hh   = 256;
constexpr int BFc  = Bb * Ff;     // 8192

// v_init weight norm: 1 / (sum_{i=0}^{12} 0.9^i * 13)
constexpr float WNORM = 1.0f / (7.458134171670999f * 13.0f);
constexpr float LN09  = -0.10536051565782628f;   // ln(0.9)

// ---- fast math (tolerance 1.8e-2; these are ~1e-7 relative) ----
__device__ __forceinline__ float frcp(float x)  { return __builtin_amdgcn_rcpf(x); }
__device__ __forceinline__ float fsqrtf_(float x){ return __builtin_amdgcn_sqrtf(x); }
__device__ __forceinline__ float ftanh_pos(float x) {       // x >= 0
    const float e = __expf(fminf(2.f * x, 30.f));           // v_exp_f32
    return (e - 1.f) * frcp(e + 1.f);
}
__device__ __forceinline__ float fatanh01(float x) {        // 0 <= x <= MAXNF
    return 0.5f * __logf((1.f + x) * frcp(1.f - x));        // v_log_f32
}

__device__ __forceinline__ float wsum64(float v) {
#pragma unroll
    for (int off = 1; off < 64; off <<= 1) v += __shfl_xor(v, off, 64);
    return v;
}

// ---------------- fused kernel: one block (4 waves) per bf ----------------
// wave wid = component c during branch phase, = horizon t during fusion.
// lane owns dims d0=2*lane, d1=2*lane+1. Uniform scalar chains are
// lane-parallelized (lane j computes step j, results broadcast via shfl).
__global__ __launch_bounds__(256, 4) void fused_kernel(
    const float* __restrict__ trend, const float* __restrict__ scoarse,
    const float* __restrict__ sfine, const float* __restrict__ resid,
    const float* __restrict__ revin_w, const float* __restrict__ revin_b,
    const float* __restrict__ enc_W, const float* __restrict__ enc_b,
    const float* __restrict__ vel_W, const float* __restrict__ vel_b,
    const float* __restrict__ steps, const float* __restrict__ mobius_w,
    const float* __restrict__ rec_W1, const float* __restrict__ rec_b1,
    const float* __restrict__ rec_W2, const float* __restrict__ rec_b2,
    float* __restrict__ out, float* __restrict__ hpart)
{
    // XCD-chunking swizzle: consecutive hardware blockIdx round-robin over
    // 8 XCDs; remap so each XCD gets a contiguous bf range (input lines
    // shared by 16 consecutive f stay in one XCD's L2). 8192 = 8 * 1024.
    const int bid  = blockIdx.x;
    const int bf   = ((bid & 7) << 10) | (bid >> 3);
    const int b    = bf >> 8;
    const int f    = bf & 255;
    const int tid  = threadIdx.x;
    const int wid  = tid >> 6;     // 0..3
    const int lane = tid & 63;

    __shared__ float xs[4 * NS];       // RAW comp rows; later reused as hbuf[4*Hh]
    __shared__ float bcu[4 * Dd];      // per-comp bc (branch), then per-horizon uls
    __shared__ float zfl[4][Tt][Dd];   // z_fut
    __shared__ float zfns[4][Tt];      // clipped norms
    __shared__ float red[8];

    const float* cp = (wid == 0) ? trend : (wid == 1) ? scoarse
                    : (wid == 2) ? sfine : resid;

    // ---- stage raw component rows (each wave its component) ----
    for (int i = lane; i < NS; i += 64)
        xs[wid * NS + i] = cp[(b * Ll + i) * Ff + f];
    __syncthreads();

    // ---- RevIN stats on combined signal ----
    float sum = 0.f, sumsq = 0.f;
    for (int l = tid; l < NS; l += 256) {
        const float x = xs[l] + xs[NS + l] + xs[2 * NS + l] + xs[3 * NS + l];
        sum += x; sumsq += x * x;
    }
    sum = wsum64(sum); sumsq = wsum64(sumsq);
    if (lane == 0) { red[wid] = sum; red[4 + wid] = sumsq; }
    __syncthreads();
    sum   = red[0] + red[1] + red[2] + red[3];
    sumsq = red[4] + red[5] + red[6] + red[7];
    const float mean    = sum * (1.f / (float)NS);
    const float stdv    = fsqrtf_(sumsq * (1.f / (float)NS) - mean * mean + 1e-5f);
    const float inv_std = frcp(stdv);
    const float rw = revin_w[f], rb = revin_b[f];
    // affine fold: scaled = raw * a_aff + k_aff
    const float a_aff = inv_std * rw;
    const float k_aff = 0.25f * (rb - mean * a_aff);

    // ================= branch (component c = wid) =================
    const int c = wid;
    const float4* xv4 = reinterpret_cast<const float4*>(xs + c * NS);
    const float* Wep  = enc_W + c * SEGc * Dd + 2 * lane;
    const float* Wvp  = vel_W + c * Dd * Dd + 2 * lane;

    float2 wreg[SEGc];
#pragma unroll
    for (int s = 0; s < SEGc; ++s)
        wreg[s] = *reinterpret_cast<const float2*>(Wep + s * Dd);
    const float2 be = *reinterpret_cast<const float2*>(enc_b + c * Dd + 2 * lane);
    const float2 bv = *reinterpret_cast<const float2*>(vel_b + c * Dd + 2 * lane);

    // column sums for the affine fold
    float cs0 = 0.f, cs1 = 0.f;
#pragma unroll
    for (int s = 0; s < SEGc; ++s) { cs0 += wreg[s].x; cs1 += wreg[s].y; }
    const float kb0 = fmaf(k_aff, cs0, be.x);
    const float kb1 = fmaf(k_aff, cs1, be.y);

    // --- Phase A: all 14 encoder dots on RAW data (independent) ---
    float y0[Nn], y1[Nn], qn[Nn];
#pragma unroll
    for (int n = 0; n < Nn; ++n) {
        float a = 0.f, d = 0.f;
#pragma unroll
        for (int q = 0; q < SEGc / 4; ++q) {
            const float4 xv = xv4[n * (SEGc / 4) + q];
            a = fmaf(xv.x, wreg[4*q+0].x, a); d = fmaf(xv.x, wreg[4*q+0].y, d);
            a = fmaf(xv.y, wreg[4*q+1].x, a); d = fmaf(xv.y, wreg[4*q+1].y, d);
            a = fmaf(xv.z, wreg[4*q+2].x, a); d = fmaf(xv.z, wreg[4*q+2].y, d);
            a = fmaf(xv.w, wreg[4*q+3].x, a); d = fmaf(xv.w, wreg[4*q+3].y, d);
        }
        a = fmaf(a_aff, a, kb0); d = fmaf(a_aff, d, kb1);
        y0[n] = a; y1[n] = d; qn[n] = a * a + d * d;
    }
    // --- neighbor dots, then 27 butterflies interleaved per stage ---
    float rd[Nn - 1];
#pragma unroll
    for (int n = 1; n < Nn; ++n)
        rd[n - 1] = y0[n - 1] * y0[n] + y1[n - 1] * y1[n];
#pragma unroll
    for (int off = 1; off < 64; off <<= 1) {
#pragma unroll
        for (int n = 0; n < Nn; ++n) qn[n] += __shfl_xor(qn[n], off, 64);
#pragma unroll
        for (int j = 0; j < Nn - 1; ++j) rd[j] += __shfl_xor(rd[j], off, 64);
    }

    // --- lane-parallel per-n projection: lane n handles segment n ---
    float qn_own = qn[0], rd_own = rd[0];
#pragma unroll
    for (int n = 1; n < Nn; ++n)     qn_own = (lane == n) ? qn[n] : qn_own;
#pragma unroll
    for (int j = 1; j < Nn - 1; ++j) rd_own = (lane == j) ? rd[j] : rd_own;

    const float vn = fsqrtf_(fmaxf(qn_own, EPSF * EPSF));
    const float th = ftanh_pos(vn);
    float s_own = th * frcp(vn);
    float nrm = th;
    if (nrm > MAXNF) { s_own *= MAXNF * frcp(nrm); nrm = MAXNF; }
    const float zn2_own = nrm * nrm;

    // neighbors for logmap step j (lane j needs j-1's values)
    const float s_prev   = __shfl(s_own,   lane - 1, 64);
    const float zn2_prev = __shfl(zn2_own, lane - 1, 64);
    const float rd_prev  = __shfl(rd_own,  lane - 1, 64);  // rd[j-1] at lane j

    // --- logmap step j computed once at lane j (valid j = 1..13) ---
    const float xyv  = -(s_prev * s_own * rd_prev);
    const float x2v  = zn2_prev, yy2 = zn2_own;
    const float c1v  = 1.f + 2.f * xyv + yy2;
    const float c2v  = 1.f - x2v;
    const float rdenv = frcp(fmaxf(1.f + 2.f * xyv + x2v * yy2, EPSF));
    const float un2 = rdenv * rdenv *
        (c1v * c1v * x2v + 2.f * c1v * c2v * xyv + c2v * c2v * yy2);
    const float un  = fsqrtf_(fmaxf(un2, EPSF * EPSF));
    const float lf  = fmaxf(1.f - x2v, EPSF);            // 2/lam
    const float gml = lf * fatanh01(fminf(un, MAXNF)) * frcp(un);
    const float wj  = WNORM * __expf(LN09 * (float)(13 - lane));  // 0.9^(13-j)
    const float gw  = wj * gml * rdenv;
    const float g1_own = -gw * c1v * s_prev;   // contribution to coef[j-1]
    const float g2_own =  gw * c2v * s_own;    // contribution to coef[j]

    // coef[n] = g2 from step n  +  g1 from step n+1 ; vi = sum coef[n]*y[n]
    float vi0 = 0.f, vi1 = 0.f;
#pragma unroll
    for (int n = 0; n < Nn; ++n) {
        float cf = (n >= 1) ? __shfl(g2_own, n, 64) : 0.f;
        if (n <= Nn - 2) cf += __shfl(g1_own, n + 1, 64);
        vi0 = fmaf(cf, y0[n], vi0);
        vi1 = fmaf(cf, y1[n], vi1);
    }
    const float sc_last = __shfl(s_own,   Nn - 1, 64);
    const float x2l     = __shfl(zn2_own, Nn - 1, 64);
    const float z0l = y0[Nn-1] * sc_last, z1l = y1[Nn-1] * sc_last;

    // --- v0t = projx(expmap0(logmap0(v_init) @ Wv + bv)) ---
    const float vin2 = wsum64(vi0 * vi0 + vi1 * vi1);
    const float vin  = fsqrtf_(fmaxf(vin2, EPSF * EPSF));
    const float lgv  = fatanh01(fminf(vin, MAXNF)) * frcp(vin);
    float* bc = bcu + c * Dd;
    *reinterpret_cast<float2*>(bc + 2 * lane) = make_float2(lgv * vi0, lgv * vi1);
    __syncthreads();

    float m0 = bv.x, m1 = bv.y;
    {
        const float4* bc4 = reinterpret_cast<const float4*>(bc);
#pragma unroll 4
        for (int kb = 0; kb < Dd / 8; ++kb) {      // 8-deep load batches
            float2 w[8];
#pragma unroll
            for (int r = 0; r < 8; ++r)
                w[r] = *reinterpret_cast<const float2*>(Wvp + (8*kb+r) * Dd);
            const float4 ta = bc4[2*kb], tb = bc4[2*kb+1];
            m0 = fmaf(ta.x, w[0].x, m0); m1 = fmaf(ta.x, w[0].y, m1);
            m0 = fmaf(ta.y, w[1].x, m0); m1 = fmaf(ta.y, w[1].y, m1);
            m0 = fmaf(ta.z, w[2].x, m0); m1 = fmaf(ta.z, w[2].y, m1);
            m0 = fmaf(ta.w, w[3].x, m0); m1 = fmaf(ta.w, w[3].y, m1);
            m0 = fmaf(tb.x, w[4].x, m0); m1 = fmaf(tb.x, w[4].y, m1);
            m0 = fmaf(tb.y, w[5].x, m0); m1 = fmaf(tb.y, w[5].y, m1);
            m0 = fmaf(tb.z, w[6].x, m0); m1 = fmaf(tb.z, w[6].y, m1);
            m0 = fmaf(tb.w, w[7].x, m0); m1 = fmaf(tb.w, w[7].y, m1);
        }
    }
    float mn2 = m0 * m0 + m1 * m1;
    float zdm = z0l * m0 + z1l * m1;
#pragma unroll
    for (int off = 1; off < 64; off <<= 1) {
        mn2 += __shfl_xor(mn2, off, 64);
        zdm += __shfl_xor(zdm, off, 64);
    }
    const float mn  = fsqrtf_(fmaxf(mn2, EPSF * EPSF));
    const float th2 = ftanh_pos(mn);
    float sc2 = th2 * frcp(mn);
    float v0n = th2;
    if (v0n > MAXNF) { sc2 *= MAXNF * frcp(v0n); v0n = MAXNF; }
    const float v00 = m0 * sc2, v01 = m1 * sc2;
    const float v0n2 = mn2 * sc2 * sc2;
    const float zdotv = sc2 * zdm;

    const float lamx = 2.f * frcp(fmaxf(1.f - x2l, EPSF));
    const float sig  = frcp(1.f + __expf(-steps[c]));

    // --- horizons: lane t computes scalars for t, broadcast A,B coeffs ---
    {
        const float alpha = sig * (float)(lane + 1);
        const float vtn2  = alpha * alpha * v0n2;
        const float vtn   = fsqrtf_(fmaxf(vtn2, EPSF * EPSF));
        const float gg    = ftanh_pos(0.5f * lamx * vtn);
        const float cyc   = gg * alpha * frcp(vtn);    // y = cyc * v0t
        const float y2    = cyc * cyc * v0n2;
        const float xy    = cyc * zdotv;
        const float c1 = 1.f + 2.f * xy + y2;
        const float c2 = 1.f - x2l;
        const float rden = frcp(fmaxf(1.f + 2.f * xy + x2l * y2, EPSF));
        float rn2 = rden * rden *
            (c1 * c1 * x2l + 2.f * c1 * c2 * xy + c2 * c2 * y2);
        float rn = fsqrtf_(fmaxf(rn2, EPSF * EPSF));
        float sclip = 1.f;
        if (rn > MAXNF) { sclip = MAXNF * frcp(rn); rn = MAXNF; }
        const float At_own = c1 * rden * sclip;        // coeff of z_last
        const float Bt_own = c2 * cyc * rden * sclip;  // coeff of v0t
        if (lane < Tt) zfns[c][lane] = rn;
#pragma unroll
        for (int t = 0; t < Tt; ++t) {
            const float A = __shfl(At_own, t, 64);
            const float B = __shfl(Bt_own, t, 64);
            const float r0 = fmaf(A, z0l, B * v00);
            const float r1 = fmaf(A, z1l, B * v01);
            *reinterpret_cast<float2*>(&zfl[c][t][2 * lane]) = make_float2(r0, r1);
        }
    }
    __syncthreads();

    // ======= Mobius fusion via Gram matrix: wave wid = horizon t =======
    {
        float mw0 = mobius_w[0], mw1 = mobius_w[1], mw2 = mobius_w[2], mw3 = mobius_w[3];
        const float mx = fmaxf(fmaxf(mw0, mw1), fmaxf(mw2, mw3));
        mw0 = __expf(mw0 - mx); mw1 = __expf(mw1 - mx);
        mw2 = __expf(mw2 - mx); mw3 = __expf(mw3 - mx);
        const float rse = frcp(mw0 + mw1 + mw2 + mw3);

        const int t = wid;
        float2 e[4];
#pragma unroll
        for (int i = 0; i < 4; ++i)
            e[i] = *reinterpret_cast<const float2*>(&zfl[i][t][2 * lane]);

        float gp[6];
        gp[0] = e[0].x * e[1].x + e[0].y * e[1].y;   // G01
        gp[1] = e[0].x * e[2].x + e[0].y * e[2].y;   // G02
        gp[2] = e[0].x * e[3].x + e[0].y * e[3].y;   // G03
        gp[3] = e[1].x * e[2].x + e[1].y * e[2].y;   // G12
        gp[4] = e[1].x * e[3].x + e[1].y * e[3].y;   // G13
        gp[5] = e[2].x * e[3].x + e[2].y * e[3].y;   // G23
#pragma unroll
        for (int off = 1; off < 64; off <<= 1) {
#pragma unroll
            for (int k = 0; k < 6; ++k) gp[k] += __shfl_xor(gp[k], off, 64);
        }

        // sm_i computed once at lane i (i = lane&3), broadcast
        const int il = lane & 3;
        float mwv_own = mw0 * rse;
        mwv_own = (il == 1) ? mw1 * rse : mwv_own;
        mwv_own = (il == 2) ? mw2 * rse : mwv_own;
        mwv_own = (il == 3) ? mw3 * rse : mwv_own;
        const float xn_own = zfns[il][t];
        const float smc = ftanh_pos(mwv_own * fatanh01(xn_own)) * frcp(xn_own);
        const float sm[4] = {__shfl(smc, 0, 64), __shfl(smc, 1, 64),
                             __shfl(smc, 2, 64), __shfl(smc, 3, 64)};

        const float xn[4] = {zfns[0][t], zfns[1][t], zfns[2][t], zfns[3][t]};
        const float Gd[4] = {xn[0]*xn[0], xn[1]*xn[1], xn[2]*xn[2], xn[3]*xn[3]};
        const float G[4][4] = {
            {Gd[0], gp[0], gp[1], gp[2]},
            {gp[0], Gd[1], gp[3], gp[4]},
            {gp[1], gp[3], Gd[2], gp[5]},
            {gp[2], gp[4], gp[5], Gd[3]}};

        float a0 = sm[0], a1 = 0.f, a2 = 0.f, a3 = 0.f;
        float cn2 = sm[0] * sm[0] * Gd[0];
#pragma unroll
        for (int i = 1; i < 4; ++i) {
            const float si = sm[i];
            const float xy = si * (a0 * G[0][i] + a1 * G[1][i] + a2 * G[2][i] + a3 * G[3][i]);
            const float y2 = si * si * Gd[i];
            const float c1 = 1.f + 2.f * xy + y2;
            const float c2 = 1.f - cn2;
            const float rden = frcp(fmaxf(1.f + 2.f * xy + cn2 * y2, EPSF));
            const float f1 = rden * c1, f2 = rden * c2 * si;
            a0 *= f1; a1 *= f1; a2 *= f1; a3 *= f1;
            if (i == 1) a1 += f2; else if (i == 2) a2 += f2; else a3 += f2;
            cn2 = rden * rden * (c1 * c1 * cn2 + 2.f * c1 * c2 * xy + c2 * c2 * y2);
        }
        float cn = fsqrtf_(fmaxf(cn2, EPSF * EPSF));
        float csc = 1.f;
        if (cn > MAXNF) { csc = MAXNF * frcp(cn); cn = MAXNF; }
        const float lg = fatanh01(cn) * frcp(cn) * csc;
        const float u0 = lg * (a0 * e[0].x + a1 * e[1].x + a2 * e[2].x + a3 * e[3].x);
        const float u1 = lg * (a0 * e[0].y + a1 * e[1].y + a2 * e[2].y + a3 * e[3].y);
        *reinterpret_cast<float2*>(&bcu[t * Dd + 2 * lane]) = make_float2(u0, u1);
    }

    // ---- hinge-loss partial (wave 0) ----
    if (wid == 0) {
        float ddv = 0.f;
        if (lane < 16)
            ddv = 2.f * fatanh01(zfns[lane & 3][lane >> 2]);
        const float ddn = __shfl(ddv, lane + 1, 64);      // next comp, same t
        float hv = ((lane < 16) && ((lane & 3) != 3))
                 ? fmaxf(ddv - ddn + 0.1f, 0.f) : 0.f;
        hv = wsum64(hv);
        if (lane == 0) hpart[bf] = hv;
    }
    __syncthreads();

    // ---- reconstruction head, all 256 threads: h[t][j], j = tid ----
    {
        const float4* u4 = reinterpret_cast<const float4*>(bcu);
        float a0 = rec_b1[tid], a1 = a0, a2 = a0, a3 = a0;
        const float* w1p = rec_W1 + tid;
#pragma unroll 4
        for (int kb = 0; kb < Dd / 8; ++kb) {      // 8-deep load batches
            float wv[8];
#pragma unroll
            for (int r = 0; r < 8; ++r) wv[r] = w1p[(8*kb+r) * Hh];
#pragma unroll
            for (int r2 = 0; r2 < 2; ++r2) {
                const float4 u0 = u4[0 * (Dd/4) + 2*kb + r2];
                const float4 u1 = u4[1 * (Dd/4) + 2*kb + r2];
                const float4 u2 = u4[2 * (Dd/4) + 2*kb + r2];
                const float4 u3 = u4[3 * (Dd/4) + 2*kb + r2];
                const float wa = wv[4*r2+0], wb = wv[4*r2+1];
                const float wc = wv[4*r2+2], wd = wv[4*r2+3];
                a0 = fmaf(u0.x, wa, a0); a0 = fmaf(u0.y, wb, a0);
                a0 = fmaf(u0.z, wc, a0); a0 = fmaf(u0.w, wd, a0);
                a1 = fmaf(u1.x, wa, a1); a1 = fmaf(u1.y, wb, a1);
                a1 = fmaf(u1.z, wc, a1); a1 = fmaf(u1.w, wd, a1);
                a2 = fmaf(u2.x, wa, a2); a2 = fmaf(u2.y, wb, a2);
                a2 = fmaf(u2.z, wc, a2); a2 = fmaf(u2.w, wd, a2);
                a3 = fmaf(u3.x, wa, a3); a3 = fmaf(u3.y, wb, a3);
                a3 = fmaf(u3.z, wc, a3); a3 = fmaf(u3.w, wd, a3);
            }
        }
        xs[0 * Hh + tid] = fmaxf(a0, 0.f);
        xs[1 * Hh + tid] = fmaxf(a1, 0.f);
        xs[2 * Hh + tid] = fmaxf(a2, 0.f);
        xs[3 * Hh + tid] = fmaxf(a3, 0.f);
    }
    __syncthreads();

    // ---- seg outputs: 96 of them, threads 0..95 ----
    if (tid < Tt * SEGc) {
        const int t = tid / SEGc, s = tid - t * SEGc;
        const float4* h4 = reinterpret_cast<const float4*>(xs + t * Hh);
        const float* w2p = rec_W2 + s;
        float acc = rec_b2[s];
#pragma unroll 8
        for (int jb = 0; jb < Hh / 8; ++jb) {
            float wv[8];
#pragma unroll
            for (int r = 0; r < 8; ++r) wv[r] = w2p[(8*jb+r) * SEGc];
            const float4 ha = h4[2*jb], hb = h4[2*jb+1];
            acc = fmaf(ha.x, wv[0], acc); acc = fmaf(ha.y, wv[1], acc);
            acc = fmaf(ha.z, wv[2], acc); acc = fmaf(ha.w, wv[3], acc);
            acc = fmaf(hb.x, wv[4], acc); acc = fmaf(hb.y, wv[5], acc);
            acc = fmaf(hb.z, wv[6], acc); acc = fmaf(hb.w, wv[7], acc);
        }
        const float val = (acc - rb) * frcp(rw) * stdv + mean;   // RevIN denorm
        out[(b * (Tt * SEGc) + tid) * Ff + f] = val;
    }
}

// ---------------- deterministic hloss reduction ----------------
__global__ __launch_bounds__(256) void hloss_kernel(
    const float* __restrict__ hpart, float* __restrict__ out)
{
    __shared__ float sm[256];
    const int tid = threadIdx.x;
    float s = 0.f;
    for (int i = tid; i < BFc; i += 256) s += hpart[i];
    sm[tid] = s;
    __syncthreads();
    for (int off = 128; off > 0; off >>= 1) {
        if (tid < off) sm[tid] += sm[tid + off];
        __syncthreads();
    }
    if (tid == 0) out[Bb * Tt * SEGc * Ff] = sm[0] / (float)(BFc * Tt);
}

extern "C" void kernel_launch(void* const* d_in, const int* in_sizes, int n_in,
                              void* d_out, int out_size, void* d_ws, size_t ws_size,
                              hipStream_t stream) {
    const float* trend   = (const float*)d_in[0];
    const float* scoarse = (const float*)d_in[1];
    const float* sfine   = (const float*)d_in[2];
    const float* resid   = (const float*)d_in[3];
    const float* revin_w = (const float*)d_in[4];
    const float* revin_b = (const float*)d_in[5];
    const float* enc_W   = (const float*)d_in[6];
    const float* enc_b   = (const float*)d_in[7];
    const float* vel_W   = (const float*)d_in[8];
    const float* vel_b   = (const float*)d_in[9];
    const float* steps   = (const float*)d_in[10];
    const float* mobw    = (const float*)d_in[11];
    const float* rec_W1  = (const float*)d_in[12];
    const float* rec_b1  = (const float*)d_in[13];
    const float* rec_W2  = (const float*)d_in[14];
    const float* rec_b2  = (const float*)d_in[15];

    float* out = (float*)d_out;
    float* wsf = (float*)d_ws;           // hpart[8192]

    fused_kernel<<<BFc, 256, 0, stream>>>(
        trend, scoarse, sfine, resid, revin_w, revin_b,
        enc_W, enc_b, vel_W, vel_b, steps, mobw,
        rec_W1, rec_b1, rec_W2, rec_b2,
        out, wsf);
    hloss_kernel<<<1, 256, 0, stream>>>(wsf, out);
}

// Round 7
// 229.732 us; speedup vs baseline: 1.4718x; 1.2306x over previous
//
#include <hip/hip_runtime.h>
#include <math.h>

#define EPSF 1e-5f
#define MAXNF (1.0f - 1e-5f)

constexpr int SEGc = 24;
constexpr int Nn   = 14;          // L / SEG
constexpr int NS   = Nn * SEGc;   // 336
constexpr int Tt   = 4;           // horizons
constexpr int Bb   = 32;
constexpr int Ll   = 336;
constexpr int Ff   = 256;
constexpr int Dd   = 128;
constexpr int Hh   = 256;
constexpr int BFc  = Bb * Ff;     // 8192

// v_init weight norm: 1 / (sum_{i=0}^{12} 0.9^i * 13)
constexpr float WNORM = 1.0f / (7.458134171670999f * 13.0f);
constexpr float LN09  = -0.10536051565782628f;   // ln(0.9)

// ---- fast math (tolerance 1.8e-2; these are ~1e-7 relative) ----
__device__ __forceinline__ float frcp(float x)  { return __builtin_amdgcn_rcpf(x); }
__device__ __forceinline__ float fsqrtf_(float x){ return __builtin_amdgcn_sqrtf(x); }
__device__ __forceinline__ float ftanh_pos(float x) {       // x >= 0
    const float e = __expf(fminf(2.f * x, 30.f));           // v_exp_f32
    return (e - 1.f) * frcp(e + 1.f);
}
__device__ __forceinline__ float fatanh01(float x) {        // 0 <= x <= MAXNF
    return 0.5f * __logf((1.f + x) * frcp(1.f - x));        // v_log_f32
}

// ---------------- fused kernel: one block (4 waves) per bf PAIR ----------------
// Block handles bf0 = 2k (even f) and bf1 = 2k+1 — same b, adjacent f.
// wave wid = component c; lane owns dims d0=2*lane, d1=2*lane+1 for BOTH bf.
// Uniform scalar chains lane-parallel: lanes 0-15 do bf0 items, 16-31 bf1.
__global__ __launch_bounds__(256, 4) void fused_kernel(
    const float* __restrict__ trend, const float* __restrict__ scoarse,
    const float* __restrict__ sfine, const float* __restrict__ resid,
    const float* __restrict__ revin_w, const float* __restrict__ revin_b,
    const float* __restrict__ enc_W, const float* __restrict__ enc_b,
    const float* __restrict__ vel_W, const float* __restrict__ vel_b,
    const float* __restrict__ steps, const float* __restrict__ mobius_w,
    const float* __restrict__ rec_W1, const float* __restrict__ rec_b1,
    const float* __restrict__ rec_W2, const float* __restrict__ rec_b2,
    float* __restrict__ out, float* __restrict__ hpart)
{
    // XCD-chunking swizzle over 4096 pair-blocks (8 XCDs x 512 chunk).
    const int bid   = blockIdx.x;
    const int kpair = ((bid & 7) << 9) | (bid >> 3);   // 0..4095
    const int bf0   = kpair << 1;
    const int b     = bf0 >> 8;
    const int f0    = bf0 & 255;          // even
    const int tid   = threadIdx.x;
    const int wid   = tid >> 6;           // 0..3 = component
    const int lane  = tid & 63;
    const int gi    = lane & 15;          // item index within group
    const int pg    = (lane >> 4) & 1;    // group p (meaningful for lanes 0..31)

    __shared__ float xs[8 * NS];          // [p][c][NS] raw rows; later hbuf[p][t][Hh]
    __shared__ float bcu[8 * Dd];         // [p][c][Dd] bc; later [p][t][Dd] uls
    __shared__ float zfl[2][4][Tt][Dd];   // z_fut per p
    __shared__ float zfns[2][4][Tt];      // clipped norms per p
    __shared__ float red[16];

    const float* cp = (wid == 0) ? trend : (wid == 1) ? scoarse
                    : (wid == 2) ? sfine : resid;

    // ---- stage raw rows: one float2 load serves both bf ----
    for (int i = lane; i < NS; i += 64) {
        const float2 v = *reinterpret_cast<const float2*>(&cp[(b * Ll + i) * Ff + f0]);
        xs[(0 * 4 + wid) * NS + i] = v.x;
        xs[(1 * 4 + wid) * NS + i] = v.y;
    }
    __syncthreads();

    // ---- RevIN stats for both bf ----
    float s0 = 0.f, q0 = 0.f, s1 = 0.f, q1 = 0.f;
    for (int l = tid; l < NS; l += 256) {
        const float x0 = xs[l] + xs[NS + l] + xs[2 * NS + l] + xs[3 * NS + l];
        const float x1 = xs[4 * NS + l] + xs[5 * NS + l] + xs[6 * NS + l] + xs[7 * NS + l];
        s0 += x0; q0 += x0 * x0; s1 += x1; q1 += x1 * x1;
    }
#pragma unroll
    for (int off = 1; off < 64; off <<= 1) {
        s0 += __shfl_xor(s0, off, 64); q0 += __shfl_xor(q0, off, 64);
        s1 += __shfl_xor(s1, off, 64); q1 += __shfl_xor(q1, off, 64);
    }
    if (lane == 0) {
        red[wid] = s0; red[4 + wid] = q0; red[8 + wid] = s1; red[12 + wid] = q1;
    }
    __syncthreads();
    s0 = red[0] + red[1] + red[2] + red[3];
    q0 = red[4] + red[5] + red[6] + red[7];
    s1 = red[8] + red[9] + red[10] + red[11];
    q1 = red[12] + red[13] + red[14] + red[15];
    const float mean0 = s0 * (1.f / (float)NS);
    const float stdv0 = fsqrtf_(q0 * (1.f / (float)NS) - mean0 * mean0 + 1e-5f);
    const float mean1 = s1 * (1.f / (float)NS);
    const float stdv1 = fsqrtf_(q1 * (1.f / (float)NS) - mean1 * mean1 + 1e-5f);
    const float rw0v = revin_w[f0],     rb0v = revin_b[f0];
    const float rw1v = revin_w[f0 + 1], rb1v = revin_b[f0 + 1];
    const float aff0 = frcp(stdv0) * rw0v;
    const float kaf0 = 0.25f * (rb0v - mean0 * aff0);
    const float aff1 = frcp(stdv1) * rw1v;
    const float kaf1 = 0.25f * (rb1v - mean1 * aff1);

    // ================= branch (component c = wid, both bf) =================
    const int c = wid;
    const float4* xv40 = reinterpret_cast<const float4*>(xs + (0 * 4 + c) * NS);
    const float4* xv41 = reinterpret_cast<const float4*>(xs + (1 * 4 + c) * NS);
    const float* Wep = enc_W + c * SEGc * Dd + 2 * lane;
    const float* Wvp = vel_W + c * Dd * Dd + 2 * lane;

    float2 wreg[SEGc];
#pragma unroll
    for (int s = 0; s < SEGc; ++s)
        wreg[s] = *reinterpret_cast<const float2*>(Wep + s * Dd);
    const float2 be = *reinterpret_cast<const float2*>(enc_b + c * Dd + 2 * lane);
    const float2 bv = *reinterpret_cast<const float2*>(vel_b + c * Dd + 2 * lane);

    float cs0 = 0.f, cs1 = 0.f;
#pragma unroll
    for (int s = 0; s < SEGc; ++s) { cs0 += wreg[s].x; cs1 += wreg[s].y; }
    const float kb00 = fmaf(kaf0, cs0, be.x), kb01 = fmaf(kaf0, cs1, be.y);
    const float kb10 = fmaf(kaf1, cs0, be.x), kb11 = fmaf(kaf1, cs1, be.y);

    // --- Phase A: 28 encoder dots (14 per bf), weights shared ---
    float y00[Nn], y01[Nn], y10[Nn], y11[Nn];
#pragma unroll
    for (int n = 0; n < Nn; ++n) {
        float a0 = 0.f, d0 = 0.f, a1 = 0.f, d1 = 0.f;
#pragma unroll
        for (int q = 0; q < SEGc / 4; ++q) {
            const float4 xa = xv40[n * (SEGc / 4) + q];
            const float4 xb = xv41[n * (SEGc / 4) + q];
            a0 = fmaf(xa.x, wreg[4*q+0].x, a0); d0 = fmaf(xa.x, wreg[4*q+0].y, d0);
            a1 = fmaf(xb.x, wreg[4*q+0].x, a1); d1 = fmaf(xb.x, wreg[4*q+0].y, d1);
            a0 = fmaf(xa.y, wreg[4*q+1].x, a0); d0 = fmaf(xa.y, wreg[4*q+1].y, d0);
            a1 = fmaf(xb.y, wreg[4*q+1].x, a1); d1 = fmaf(xb.y, wreg[4*q+1].y, d1);
            a0 = fmaf(xa.z, wreg[4*q+2].x, a0); d0 = fmaf(xa.z, wreg[4*q+2].y, d0);
            a1 = fmaf(xb.z, wreg[4*q+2].x, a1); d1 = fmaf(xb.z, wreg[4*q+2].y, d1);
            a0 = fmaf(xa.w, wreg[4*q+3].x, a0); d0 = fmaf(xa.w, wreg[4*q+3].y, d0);
            a1 = fmaf(xb.w, wreg[4*q+3].x, a1); d1 = fmaf(xb.w, wreg[4*q+3].y, d1);
        }
        y00[n] = fmaf(aff0, a0, kb00); y01[n] = fmaf(aff0, d0, kb01);
        y10[n] = fmaf(aff1, a1, kb10); y11[n] = fmaf(aff1, d1, kb11);
    }

    // --- |y_n|^2 for both bf: 28 butterflies interleaved ---
    float qnv[2][Nn];
#pragma unroll
    for (int n = 0; n < Nn; ++n) {
        qnv[0][n] = y00[n] * y00[n] + y01[n] * y01[n];
        qnv[1][n] = y10[n] * y10[n] + y11[n] * y11[n];
    }
#pragma unroll
    for (int off = 1; off < 64; off <<= 1) {
#pragma unroll
        for (int n = 0; n < Nn; ++n) {
            qnv[0][n] += __shfl_xor(qnv[0][n], off, 64);
            qnv[1][n] += __shfl_xor(qnv[1][n], off, 64);
        }
    }
    // select own item: lanes 0-15 -> bf0 seg gi, lanes 16-31 -> bf1 seg gi
    float qsel0 = qnv[0][0], qsel1 = qnv[1][0];
#pragma unroll
    for (int n = 1; n < Nn; ++n) {
        qsel0 = (gi == n) ? qnv[0][n] : qsel0;
        qsel1 = (gi == n) ? qnv[1][n] : qsel1;
    }
    const float qn_own = pg ? qsel1 : qsel0;

    // --- per-segment projection, one transcendental pass for both bf ---
    const float vn = fsqrtf_(fmaxf(qn_own, EPSF * EPSF));
    const float th = ftanh_pos(vn);
    float s_own = th * frcp(vn);
    float nrm = th;
    if (nrm > MAXNF) { s_own *= MAXNF * frcp(nrm); nrm = MAXNF; }
    const float zn2_own = nrm * nrm;

    // --- neighbor dots for both bf: 26 butterflies interleaved ---
    float rdv[2][Nn - 1];
#pragma unroll
    for (int n = 1; n < Nn; ++n) {
        rdv[0][n - 1] = y00[n - 1] * y00[n] + y01[n - 1] * y01[n];
        rdv[1][n - 1] = y10[n - 1] * y10[n] + y11[n - 1] * y11[n];
    }
#pragma unroll
    for (int off = 1; off < 64; off <<= 1) {
#pragma unroll
        for (int j = 0; j < Nn - 1; ++j) {
            rdv[0][j] += __shfl_xor(rdv[0][j], off, 64);
            rdv[1][j] += __shfl_xor(rdv[1][j], off, 64);
        }
    }
    float rsel0 = rdv[0][0], rsel1 = rdv[1][0];
#pragma unroll
    for (int n = 1; n < Nn - 1; ++n) {
        rsel0 = (gi == n) ? rdv[0][n] : rsel0;
        rsel1 = (gi == n) ? rdv[1][n] : rsel1;
    }
    const float rd_own = pg ? rsel1 : rsel0;

    // --- logmap step j at lane (16p + j), j = 1..13, one pass ---
    const float s_prev   = __shfl(s_own,   lane - 1, 64);
    const float zn2_prev = __shfl(zn2_own, lane - 1, 64);
    const float rd_prev  = __shfl(rd_own,  lane - 1, 64);   // rd[j-1] at lane j

    const float xyv  = -(s_prev * s_own * rd_prev);
    const float x2v  = zn2_prev, yy2 = zn2_own;
    const float c1v  = 1.f + 2.f * xyv + yy2;
    const float c2v  = 1.f - x2v;
    const float rdenv = frcp(fmaxf(1.f + 2.f * xyv + x2v * yy2, EPSF));
    const float un2 = rdenv * rdenv *
        (c1v * c1v * x2v + 2.f * c1v * c2v * xyv + c2v * c2v * yy2);
    const float un  = fsqrtf_(fmaxf(un2, EPSF * EPSF));
    const float lf  = fmaxf(1.f - x2v, EPSF);               // 2/lam
    const float gml = lf * fatanh01(fminf(un, MAXNF)) * frcp(un);
    const float wj  = WNORM * __expf(LN09 * (float)(13 - gi));  // 0.9^(13-j)
    const float gw  = wj * gml * rdenv;
    const float g1_own = -gw * c1v * s_prev;   // contribution to coef[j-1]
    const float g2_own =  gw * c2v * s_own;    // contribution to coef[j]

    // --- v_init for both bf ---
    float vi00 = 0.f, vi01 = 0.f, vi10 = 0.f, vi11 = 0.f;
#pragma unroll
    for (int n = 0; n < Nn; ++n) {
        float cf0 = 0.f, cf1 = 0.f;
        if (n >= 1)      { cf0 = __shfl(g2_own, n, 64);       cf1 = __shfl(g2_own, 16 + n, 64); }
        if (n <= Nn - 2) { cf0 += __shfl(g1_own, n + 1, 64);  cf1 += __shfl(g1_own, 17 + n, 64); }
        vi00 = fmaf(cf0, y00[n], vi00); vi01 = fmaf(cf0, y01[n], vi01);
        vi10 = fmaf(cf1, y10[n], vi10); vi11 = fmaf(cf1, y11[n], vi11);
    }
    const float scl0 = __shfl(s_own, 13, 64),  x2l0 = __shfl(zn2_own, 13, 64);
    const float scl1 = __shfl(s_own, 29, 64),  x2l1 = __shfl(zn2_own, 29, 64);
    const float z000 = y00[Nn-1] * scl0, z010 = y01[Nn-1] * scl0;  // z_last bf0
    const float z100 = y10[Nn-1] * scl1, z110 = y11[Nn-1] * scl1;  // z_last bf1

    // --- logmap0(v_init) -> bcu ---
    float vin20 = vi00 * vi00 + vi01 * vi01;
    float vin21 = vi10 * vi10 + vi11 * vi11;
#pragma unroll
    for (int off = 1; off < 64; off <<= 1) {
        vin20 += __shfl_xor(vin20, off, 64);
        vin21 += __shfl_xor(vin21, off, 64);
    }
    const float vinn0 = fsqrtf_(fmaxf(vin20, EPSF * EPSF));
    const float lgv0  = fatanh01(fminf(vinn0, MAXNF)) * frcp(vinn0);
    const float vinn1 = fsqrtf_(fmaxf(vin21, EPSF * EPSF));
    const float lgv1  = fatanh01(fminf(vinn1, MAXNF)) * frcp(vinn1);
    *reinterpret_cast<float2*>(&bcu[(0 * 4 + c) * Dd + 2 * lane]) =
        make_float2(lgv0 * vi00, lgv0 * vi01);
    *reinterpret_cast<float2*>(&bcu[(4 + c) * Dd + 2 * lane]) =
        make_float2(lgv1 * vi10, lgv1 * vi11);
    __syncthreads();

    // --- vel matmul: weight loads shared across both bf ---
    float m00 = bv.x, m01 = bv.y, m10 = bv.x, m11 = bv.y;
    {
        const float4* bc40 = reinterpret_cast<const float4*>(bcu + (0 * 4 + c) * Dd);
        const float4* bc41 = reinterpret_cast<const float4*>(bcu + (4 + c) * Dd);
#pragma unroll 4
        for (int kb = 0; kb < Dd / 8; ++kb) {
            float2 w[8];
#pragma unroll
            for (int r = 0; r < 8; ++r)
                w[r] = *reinterpret_cast<const float2*>(Wvp + (8 * kb + r) * Dd);
            const float4 ta0 = bc40[2*kb], tb0 = bc40[2*kb+1];
            const float4 ta1 = bc41[2*kb], tb1 = bc41[2*kb+1];
#define VROW(t0, t1, r) \
            m00 = fmaf(t0, w[r].x, m00); m01 = fmaf(t0, w[r].y, m01); \
            m10 = fmaf(t1, w[r].x, m10); m11 = fmaf(t1, w[r].y, m11);
            VROW(ta0.x, ta1.x, 0) VROW(ta0.y, ta1.y, 1)
            VROW(ta0.z, ta1.z, 2) VROW(ta0.w, ta1.w, 3)
            VROW(tb0.x, tb1.x, 4) VROW(tb0.y, tb1.y, 5)
            VROW(tb0.z, tb1.z, 6) VROW(tb0.w, tb1.w, 7)
#undef VROW
        }
    }
    float mn20 = m00 * m00 + m01 * m01, zdm0 = z000 * m00 + z010 * m01;
    float mn21 = m10 * m10 + m11 * m11, zdm1 = z100 * m10 + z110 * m11;
#pragma unroll
    for (int off = 1; off < 64; off <<= 1) {
        mn20 += __shfl_xor(mn20, off, 64); zdm0 += __shfl_xor(zdm0, off, 64);
        mn21 += __shfl_xor(mn21, off, 64); zdm1 += __shfl_xor(zdm1, off, 64);
    }

    // --- expmap0 of velocity + horizon scalars, lane-parallel over (p, t) ---
    const float sig = frcp(1.f + __expf(-steps[c]));
    {
        const float mn2g = pg ? mn21 : mn20;
        const float zdmg = pg ? zdm1 : zdm0;
        const float x2lg = pg ? x2l1 : x2l0;
        const float mng  = fsqrtf_(fmaxf(mn2g, EPSF * EPSF));
        const float thg  = ftanh_pos(mng);
        float sc2g = thg * frcp(mng);
        float v0ng = thg;
        if (v0ng > MAXNF) { sc2g *= MAXNF * frcp(v0ng); v0ng = MAXNF; }
        const float v0n2g  = mn2g * sc2g * sc2g;
        const float zdotvg = sc2g * zdmg;
        const float lamxg  = 2.f * frcp(fmaxf(1.f - x2lg, EPSF));

        const float alpha = sig * (float)(gi + 1);
        const float vtn2  = alpha * alpha * v0n2g;
        const float vtn   = fsqrtf_(fmaxf(vtn2, EPSF * EPSF));
        const float gg    = ftanh_pos(0.5f * lamxg * vtn);
        const float cyc   = gg * alpha * frcp(vtn);
        const float y2    = cyc * cyc * v0n2g;
        const float xy    = cyc * zdotvg;
        const float c1 = 1.f + 2.f * xy + y2;
        const float c2 = 1.f - x2lg;
        const float rden = frcp(fmaxf(1.f + 2.f * xy + x2lg * y2, EPSF));
        float rn2 = rden * rden *
            (c1 * c1 * x2lg + 2.f * c1 * c2 * xy + c2 * c2 * y2);
        float rn = fsqrtf_(fmaxf(rn2, EPSF * EPSF));
        float sclip = 1.f;
        if (rn > MAXNF) { sclip = MAXNF * frcp(rn); rn = MAXNF; }
        const float At_own = c1 * rden * sclip;         // coeff of z_last
        const float Bt_own = c2 * cyc * rden * sclip;   // coeff of v0t
        if (lane < 32 && gi < Tt) zfns[pg][c][gi] = rn;

        const float sc2_0 = __shfl(sc2g, 0, 64), sc2_1 = __shfl(sc2g, 16, 64);
        const float v0d00 = m00 * sc2_0, v0d01 = m01 * sc2_0;   // v0t bf0
        const float v0d10 = m10 * sc2_1, v0d11 = m11 * sc2_1;   // v0t bf1
#pragma unroll
        for (int t = 0; t < Tt; ++t) {
            const float A0 = __shfl(At_own, t, 64),      B0 = __shfl(Bt_own, t, 64);
            const float A1 = __shfl(At_own, 16 + t, 64), B1 = __shfl(Bt_own, 16 + t, 64);
            *reinterpret_cast<float2*>(&zfl[0][c][t][2 * lane]) =
                make_float2(fmaf(A0, z000, B0 * v0d00), fmaf(A0, z010, B0 * v0d01));
            *reinterpret_cast<float2*>(&zfl[1][c][t][2 * lane]) =
                make_float2(fmaf(A1, z100, B1 * v0d10), fmaf(A1, z110, B1 * v0d11));
        }
    }
    __syncthreads();

    // ======= Mobius fusion via Gram matrices: wave wid = horizon t, both bf =======
    {
        float mwa = mobius_w[0], mwb = mobius_w[1], mwc = mobius_w[2], mwd = mobius_w[3];
        const float mx = fmaxf(fmaxf(mwa, mwb), fmaxf(mwc, mwd));
        mwa = __expf(mwa - mx); mwb = __expf(mwb - mx);
        mwc = __expf(mwc - mx); mwd = __expf(mwd - mx);
        const float rse = frcp(mwa + mwb + mwc + mwd);
        const float mw[4] = {mwa * rse, mwb * rse, mwc * rse, mwd * rse};

        const int t = wid;
        float2 e0[4], e1[4];
#pragma unroll
        for (int i = 0; i < 4; ++i) {
            e0[i] = *reinterpret_cast<const float2*>(&zfl[0][i][t][2 * lane]);
            e1[i] = *reinterpret_cast<const float2*>(&zfl[1][i][t][2 * lane]);
        }
        float gp[12];
        gp[0]  = e0[0].x*e0[1].x + e0[0].y*e0[1].y;
        gp[1]  = e0[0].x*e0[2].x + e0[0].y*e0[2].y;
        gp[2]  = e0[0].x*e0[3].x + e0[0].y*e0[3].y;
        gp[3]  = e0[1].x*e0[2].x + e0[1].y*e0[2].y;
        gp[4]  = e0[1].x*e0[3].x + e0[1].y*e0[3].y;
        gp[5]  = e0[2].x*e0[3].x + e0[2].y*e0[3].y;
        gp[6]  = e1[0].x*e1[1].x + e1[0].y*e1[1].y;
        gp[7]  = e1[0].x*e1[2].x + e1[0].y*e1[2].y;
        gp[8]  = e1[0].x*e1[3].x + e1[0].y*e1[3].y;
        gp[9]  = e1[1].x*e1[2].x + e1[1].y*e1[2].y;
        gp[10] = e1[1].x*e1[3].x + e1[1].y*e1[3].y;
        gp[11] = e1[2].x*e1[3].x + e1[2].y*e1[3].y;
#pragma unroll
        for (int off = 1; off < 64; off <<= 1) {
#pragma unroll
            for (int k = 0; k < 12; ++k) gp[k] += __shfl_xor(gp[k], off, 64);
        }

        // mob_smul scales: one transcendental pass for 8 (p,i) at lanes 0-3,16-19
        const int il = lane & 3;
        float mwv_own = mw[0];
        mwv_own = (il == 1) ? mw[1] : mwv_own;
        mwv_own = (il == 2) ? mw[2] : mwv_own;
        mwv_own = (il == 3) ? mw[3] : mwv_own;
        const float xn_own = zfns[pg][il][t];
        const float smc = ftanh_pos(mwv_own * fatanh01(xn_own)) * frcp(xn_own);
        float smv[2][4];
#pragma unroll
        for (int i = 0; i < 4; ++i) {
            smv[0][i] = __shfl(smc, i, 64);
            smv[1][i] = __shfl(smc, 16 + i, 64);
        }

#pragma unroll
        for (int p = 0; p < 2; ++p) {
            const float xn0 = zfns[p][0][t], xn1 = zfns[p][1][t];
            const float xn2 = zfns[p][2][t], xn3 = zfns[p][3][t];
            const float Gd[4] = {xn0*xn0, xn1*xn1, xn2*xn2, xn3*xn3};
            const float G[4][4] = {
                {Gd[0], gp[6*p+0], gp[6*p+1], gp[6*p+2]},
                {gp[6*p+0], Gd[1], gp[6*p+3], gp[6*p+4]},
                {gp[6*p+1], gp[6*p+3], Gd[2], gp[6*p+5]},
                {gp[6*p+2], gp[6*p+4], gp[6*p+5], Gd[3]}};
            float a0 = smv[p][0], a1 = 0.f, a2 = 0.f, a3 = 0.f;
            float cn2 = smv[p][0] * smv[p][0] * Gd[0];
#pragma unroll
            for (int i = 1; i < 4; ++i) {
                const float si = smv[p][i];
                const float xy = si * (a0*G[0][i] + a1*G[1][i] + a2*G[2][i] + a3*G[3][i]);
                const float y2 = si * si * Gd[i];
                const float c1 = 1.f + 2.f * xy + y2;
                const float c2 = 1.f - cn2;
                const float rden = frcp(fmaxf(1.f + 2.f * xy + cn2 * y2, EPSF));
                const float f1 = rden * c1, f2 = rden * c2 * si;
                a0 *= f1; a1 *= f1; a2 *= f1; a3 *= f1;
                if (i == 1) a1 += f2; else if (i == 2) a2 += f2; else a3 += f2;
                cn2 = rden * rden * (c1*c1*cn2 + 2.f*c1*c2*xy + c2*c2*y2);
            }
            float cn = fsqrtf_(fmaxf(cn2, EPSF * EPSF));
            float csc = 1.f;
            if (cn > MAXNF) { csc = MAXNF * frcp(cn); cn = MAXNF; }
            const float lg = fatanh01(cn) * frcp(cn) * csc;
            const float ex0 = p ? e1[0].x : e0[0].x, ey0 = p ? e1[0].y : e0[0].y;
            const float ex1 = p ? e1[1].x : e0[1].x, ey1 = p ? e1[1].y : e0[1].y;
            const float ex2 = p ? e1[2].x : e0[2].x, ey2 = p ? e1[2].y : e0[2].y;
            const float ex3 = p ? e1[3].x : e0[3].x, ey3 = p ? e1[3].y : e0[3].y;
            const float u0 = lg * (a0*ex0 + a1*ex1 + a2*ex2 + a3*ex3);
            const float u1 = lg * (a0*ey0 + a1*ey1 + a2*ey2 + a3*ey3);
            *reinterpret_cast<float2*>(&bcu[(p * 4 + t) * Dd + 2 * lane]) =
                make_float2(u0, u1);
        }
    }

    // ---- hinge-loss partials: wave 0, lanes 0-15 bf0, 16-31 bf1 ----
    if (wid == 0) {
        float ddv = 0.f;
        if (lane < 32)
            ddv = 2.f * fatanh01(zfns[pg][lane & 3][gi >> 2]);
        const float ddn = __shfl(ddv, lane + 1, 64);
        float hv = ((lane < 32) && ((lane & 3) != 3))
                 ? fmaxf(ddv - ddn + 0.1f, 0.f) : 0.f;
#pragma unroll
        for (int off = 1; off < 16; off <<= 1) hv += __shfl_xor(hv, off, 64);
        if (lane == 0)  hpart[bf0]     = hv;
        if (lane == 16) hpart[bf0 + 1] = hv;
    }
    __syncthreads();

    // ---- reconstruction hidden layer: thread tid = hidden j, 8 accums ----
    {
        const float4* u4 = reinterpret_cast<const float4*>(bcu);
        const float bb = rec_b1[tid];
        float acc[2][4];
#pragma unroll
        for (int p = 0; p < 2; ++p)
#pragma unroll
            for (int t = 0; t < 4; ++t) acc[p][t] = bb;
        const float* w1p = rec_W1 + tid;
#pragma unroll 2
        for (int kb = 0; kb < Dd / 8; ++kb) {
            float wv[8];
#pragma unroll
            for (int r = 0; r < 8; ++r) wv[r] = w1p[(8 * kb + r) * Hh];
#pragma unroll
            for (int r2 = 0; r2 < 2; ++r2) {
#pragma unroll
                for (int p = 0; p < 2; ++p)
#pragma unroll
                    for (int t = 0; t < 4; ++t) {
                        const float4 u = u4[(p * 4 + t) * (Dd / 4) + 2 * kb + r2];
                        acc[p][t] = fmaf(u.x, wv[4*r2+0], acc[p][t]);
                        acc[p][t] = fmaf(u.y, wv[4*r2+1], acc[p][t]);
                        acc[p][t] = fmaf(u.z, wv[4*r2+2], acc[p][t]);
                        acc[p][t] = fmaf(u.w, wv[4*r2+3], acc[p][t]);
                    }
            }
        }
        // xs raw data fully consumed in Phase A (all waves past barriers) -> hbuf
#pragma unroll
        for (int p = 0; p < 2; ++p)
#pragma unroll
            for (int t = 0; t < 4; ++t)
                xs[(p * 4 + t) * Hh + tid] = fmaxf(acc[p][t], 0.f);
    }
    __syncthreads();

    // ---- seg outputs: 96 threads, each handles (t,s) for BOTH bf ----
    if (tid < Tt * SEGc) {
        const int t = tid / SEGc, s = tid - t * SEGc;
        const float4* h40 = reinterpret_cast<const float4*>(xs + (0 * 4 + t) * Hh);
        const float4* h41 = reinterpret_cast<const float4*>(xs + (4 + t) * Hh);
        const float* w2p = rec_W2 + s;
        float acc0 = rec_b2[s], acc1 = acc0;
#pragma unroll 4
        for (int jb = 0; jb < Hh / 8; ++jb) {
            float wv[8];
#pragma unroll
            for (int r = 0; r < 8; ++r) wv[r] = w2p[(8 * jb + r) * SEGc];
            const float4 ha = h40[2*jb], hb = h40[2*jb+1];
            const float4 hc = h41[2*jb], hd = h41[2*jb+1];
            acc0 = fmaf(ha.x, wv[0], acc0); acc0 = fmaf(ha.y, wv[1], acc0);
            acc0 = fmaf(ha.z, wv[2], acc0); acc0 = fmaf(ha.w, wv[3], acc0);
            acc0 = fmaf(hb.x, wv[4], acc0); acc0 = fmaf(hb.y, wv[5], acc0);
            acc0 = fmaf(hb.z, wv[6], acc0); acc0 = fmaf(hb.w, wv[7], acc0);
            acc1 = fmaf(hc.x, wv[0], acc1); acc1 = fmaf(hc.y, wv[1], acc1);
            acc1 = fmaf(hc.z, wv[2], acc1); acc1 = fmaf(hc.w, wv[3], acc1);
            acc1 = fmaf(hd.x, wv[4], acc1); acc1 = fmaf(hd.y, wv[5], acc1);
            acc1 = fmaf(hd.z, wv[6], acc1); acc1 = fmaf(hd.w, wv[7], acc1);
        }
        const float val0 = (acc0 - rb0v) * frcp(rw0v) * stdv0 + mean0;
        const float val1 = (acc1 - rb1v) * frcp(rw1v) * stdv1 + mean1;
        *reinterpret_cast<float2*>(&out[(b * (Tt * SEGc) + tid) * Ff + f0]) =
            make_float2(val0, val1);
    }
}

// ---------------- deterministic hloss reduction ----------------
__global__ __launch_bounds__(256) void hloss_kernel(
    const float* __restrict__ hpart, float* __restrict__ out)
{
    __shared__ float sm[256];
    const int tid = threadIdx.x;
    float s = 0.f;
    for (int i = tid; i < BFc; i += 256) s += hpart[i];
    sm[tid] = s;
    __syncthreads();
    for (int off = 128; off > 0; off >>= 1) {
        if (tid < off) sm[tid] += sm[tid + off];
        __syncthreads();
    }
    if (tid == 0) out[Bb * Tt * SEGc * Ff] = sm[0] / (float)(BFc * Tt);
}

extern "C" void kernel_launch(void* const* d_in, const int* in_sizes, int n_in,
                              void* d_out, int out_size, void* d_ws, size_t ws_size,
                              hipStream_t stream) {
    const float* trend   = (const float*)d_in[0];
    const float* scoarse = (const float*)d_in[1];
    const float* sfine   = (const float*)d_in[2];
    const float* resid   = (const float*)d_in[3];
    const float* revin_w = (const float*)d_in[4];
    const float* revin_b = (const float*)d_in[5];
    const float* enc_W   = (const float*)d_in[6];
    const float* enc_b   = (const float*)d_in[7];
    const float* vel_W   = (const float*)d_in[8];
    const float* vel_b   = (const float*)d_in[9];
    const float* steps   = (const float*)d_in[10];
    const float* mobw    = (const float*)d_in[11];
    const float* rec_W1  = (const float*)d_in[12];
    const float* rec_b1  = (const float*)d_in[13];
    const float* rec_W2  = (const float*)d_in[14];
    const float* rec_b2  = (const float*)d_in[15];

    float* out = (float*)d_out;
    float* wsf = (float*)d_ws;           // hpart[8192]

    fused_kernel<<<BFc / 2, 256, 0, stream>>>(
        trend, scoarse, sfine, resid, revin_w, revin_b,
        enc_W, enc_b, vel_W, vel_b, steps, mobw,
        rec_W1, rec_b1, rec_W2, rec_b2,
        out, wsf);
    hloss_kernel<<<1, 256, 0, stream>>>(wsf, out);
}

// Round 8
// 227.589 us; speedup vs baseline: 1.4857x; 1.0094x over previous
//
#include <hip/hip_runtime.h>
#include <math.h>

#define EPSF 1e-5f
#define MAXNF (1.0f - 1e-5f)

constexpr int SEGc = 24;
constexpr int Nn   = 14;          // L / SEG
constexpr int NS   = Nn * SEGc;   // 336
constexpr int Tt   = 4;           // horizons
constexpr int Bb   = 32;
constexpr int Ll   = 336;
constexpr int Ff   = 256;
constexpr int Dd   = 128;
constexpr int Hh   = 256;
constexpr int BFc  = Bb * Ff;     // 8192

// v_init weight norm: 1 / (sum_{i=0}^{12} 0.9^i * 13)
constexpr float WNORM = 1.0f / (7.458134171670999f * 13.0f);
constexpr float LN09  = -0.10536051565782628f;   // ln(0.9)

// ---- fast math (tolerance 1.8e-2; these are ~1e-7 relative) ----
__device__ __forceinline__ float frcp(float x)  { return __builtin_amdgcn_rcpf(x); }
__device__ __forceinline__ float fsqrtf_(float x){ return __builtin_amdgcn_sqrtf(x); }
__device__ __forceinline__ float ftanh_pos(float x) {       // x >= 0
    const float e = __expf(fminf(2.f * x, 30.f));           // v_exp_f32
    return (e - 1.f) * frcp(e + 1.f);
}
__device__ __forceinline__ float fatanh01(float x) {        // 0 <= x <= MAXNF
    return 0.5f * __logf((1.f + x) * frcp(1.f - x));        // v_log_f32
}

// ---------------- fused kernel: one block (4 waves) per bf PAIR ----------------
// Block handles bf0 = 2k (even f) and bf1 = 2k+1 — same b, adjacent f.
// wave wid = component c; lane owns dims d0=2*lane, d1=2*lane+1 for BOTH bf.
// Uniform scalar chains lane-parallel: lanes 0-15 do bf0 items, 16-31 bf1.
//
// LDS: one 16 KB region time-shared by xs (raw rows, dead after Phase A /
// barrier B3) -> zfl (z_fut, written after B3, dead after fusion / B5) ->
// hbuf (hidden layer, written after B5). Lifetimes separated by the existing
// barriers; aliasing cuts LDS 31.7K -> ~20.7K => 7 blocks/CU residency.
__global__ __launch_bounds__(256, 4) void fused_kernel(
    const float* __restrict__ trend, const float* __restrict__ scoarse,
    const float* __restrict__ sfine, const float* __restrict__ resid,
    const float* __restrict__ revin_w, const float* __restrict__ revin_b,
    const float* __restrict__ enc_W, const float* __restrict__ enc_b,
    const float* __restrict__ vel_W, const float* __restrict__ vel_b,
    const float* __restrict__ steps, const float* __restrict__ mobius_w,
    const float* __restrict__ rec_W1, const float* __restrict__ rec_b1,
    const float* __restrict__ rec_W2, const float* __restrict__ rec_b2,
    float* __restrict__ out, float* __restrict__ hpart)
{
    // XCD-chunking swizzle over 4096 pair-blocks (8 XCDs x 512 chunk).
    const int bid   = blockIdx.x;
    const int kpair = ((bid & 7) << 9) | (bid >> 3);   // 0..4095
    const int bf0   = kpair << 1;
    const int b     = bf0 >> 8;
    const int f0    = bf0 & 255;          // even
    const int tid   = threadIdx.x;
    const int wid   = tid >> 6;           // 0..3 = component
    const int lane  = tid & 63;
    const int gi    = lane & 15;          // item index within group
    const int pg    = (lane >> 4) & 1;    // group p (meaningful for lanes 0..31)

    __shared__ float lds_big[2 * 4 * Tt * Dd];   // 4096 floats = 16 KB, time-shared
    __shared__ float bcu[8 * Dd];                // [p][c]Dd bc; later [p][t]Dd uls
    __shared__ float zfns[2][4][Tt];             // clipped norms per p
    __shared__ float red[16];

#define XS(p, c)     (lds_big + ((p) * 4 + (c)) * NS)                 // 8*336 floats
#define ZFL(p, i, t) (lds_big + (((p) * 4 + (i)) * Tt + (t)) * Dd)    // 4096 floats
#define HB(p, t)     (lds_big + ((p) * 4 + (t)) * Hh)                 // 2048 floats

    const float* cp = (wid == 0) ? trend : (wid == 1) ? scoarse
                    : (wid == 2) ? sfine : resid;

    // ---- stage raw rows: one float2 load serves both bf ----
    for (int i = lane; i < NS; i += 64) {
        const float2 v = *reinterpret_cast<const float2*>(&cp[(b * Ll + i) * Ff + f0]);
        XS(0, wid)[i] = v.x;
        XS(1, wid)[i] = v.y;
    }
    __syncthreads();                                            // B1

    // ---- RevIN stats for both bf ----
    float s0 = 0.f, q0 = 0.f, s1 = 0.f, q1 = 0.f;
    for (int l = tid; l < NS; l += 256) {
        const float x0 = XS(0,0)[l] + XS(0,1)[l] + XS(0,2)[l] + XS(0,3)[l];
        const float x1 = XS(1,0)[l] + XS(1,1)[l] + XS(1,2)[l] + XS(1,3)[l];
        s0 += x0; q0 += x0 * x0; s1 += x1; q1 += x1 * x1;
    }
#pragma unroll
    for (int off = 1; off < 64; off <<= 1) {
        s0 += __shfl_xor(s0, off, 64); q0 += __shfl_xor(q0, off, 64);
        s1 += __shfl_xor(s1, off, 64); q1 += __shfl_xor(q1, off, 64);
    }
    if (lane == 0) {
        red[wid] = s0; red[4 + wid] = q0; red[8 + wid] = s1; red[12 + wid] = q1;
    }
    __syncthreads();                                            // B2
    s0 = red[0] + red[1] + red[2] + red[3];
    q0 = red[4] + red[5] + red[6] + red[7];
    s1 = red[8] + red[9] + red[10] + red[11];
    q1 = red[12] + red[13] + red[14] + red[15];
    const float mean0 = s0 * (1.f / (float)NS);
    const float stdv0 = fsqrtf_(q0 * (1.f / (float)NS) - mean0 * mean0 + 1e-5f);
    const float mean1 = s1 * (1.f / (float)NS);
    const float stdv1 = fsqrtf_(q1 * (1.f / (float)NS) - mean1 * mean1 + 1e-5f);
    const float rw0v = revin_w[f0],     rb0v = revin_b[f0];
    const float rw1v = revin_w[f0 + 1], rb1v = revin_b[f0 + 1];
    const float aff0 = frcp(stdv0) * rw0v;
    const float kaf0 = 0.25f * (rb0v - mean0 * aff0);
    const float aff1 = frcp(stdv1) * rw1v;
    const float kaf1 = 0.25f * (rb1v - mean1 * aff1);

    // ================= branch (component c = wid, both bf) =================
    const int c = wid;
    const float4* xv40 = reinterpret_cast<const float4*>(XS(0, c));
    const float4* xv41 = reinterpret_cast<const float4*>(XS(1, c));
    const float* Wep = enc_W + c * SEGc * Dd + 2 * lane;
    const float* Wvp = vel_W + c * Dd * Dd + 2 * lane;

    float2 wreg[SEGc];
#pragma unroll
    for (int s = 0; s < SEGc; ++s)
        wreg[s] = *reinterpret_cast<const float2*>(Wep + s * Dd);
    const float2 be = *reinterpret_cast<const float2*>(enc_b + c * Dd + 2 * lane);
    const float2 bv = *reinterpret_cast<const float2*>(vel_b + c * Dd + 2 * lane);

    float cs0 = 0.f, cs1 = 0.f;
#pragma unroll
    for (int s = 0; s < SEGc; ++s) { cs0 += wreg[s].x; cs1 += wreg[s].y; }
    const float kb00 = fmaf(kaf0, cs0, be.x), kb01 = fmaf(kaf0, cs1, be.y);
    const float kb10 = fmaf(kaf1, cs0, be.x), kb11 = fmaf(kaf1, cs1, be.y);

    // --- Phase A: 28 encoder dots (14 per bf), weights shared ---
    float y00[Nn], y01[Nn], y10[Nn], y11[Nn];
#pragma unroll
    for (int n = 0; n < Nn; ++n) {
        float a0 = 0.f, d0 = 0.f, a1 = 0.f, d1 = 0.f;
#pragma unroll
        for (int q = 0; q < SEGc / 4; ++q) {
            const float4 xa = xv40[n * (SEGc / 4) + q];
            const float4 xb = xv41[n * (SEGc / 4) + q];
            a0 = fmaf(xa.x, wreg[4*q+0].x, a0); d0 = fmaf(xa.x, wreg[4*q+0].y, d0);
            a1 = fmaf(xb.x, wreg[4*q+0].x, a1); d1 = fmaf(xb.x, wreg[4*q+0].y, d1);
            a0 = fmaf(xa.y, wreg[4*q+1].x, a0); d0 = fmaf(xa.y, wreg[4*q+1].y, d0);
            a1 = fmaf(xb.y, wreg[4*q+1].x, a1); d1 = fmaf(xb.y, wreg[4*q+1].y, d1);
            a0 = fmaf(xa.z, wreg[4*q+2].x, a0); d0 = fmaf(xa.z, wreg[4*q+2].y, d0);
            a1 = fmaf(xb.z, wreg[4*q+2].x, a1); d1 = fmaf(xb.z, wreg[4*q+2].y, d1);
            a0 = fmaf(xa.w, wreg[4*q+3].x, a0); d0 = fmaf(xa.w, wreg[4*q+3].y, d0);
            a1 = fmaf(xb.w, wreg[4*q+3].x, a1); d1 = fmaf(xb.w, wreg[4*q+3].y, d1);
        }
        y00[n] = fmaf(aff0, a0, kb00); y01[n] = fmaf(aff0, d0, kb01);
        y10[n] = fmaf(aff1, a1, kb10); y11[n] = fmaf(aff1, d1, kb11);
    }

    // --- |y_n|^2 for both bf: 28 butterflies interleaved ---
    float qnv[2][Nn];
#pragma unroll
    for (int n = 0; n < Nn; ++n) {
        qnv[0][n] = y00[n] * y00[n] + y01[n] * y01[n];
        qnv[1][n] = y10[n] * y10[n] + y11[n] * y11[n];
    }
#pragma unroll
    for (int off = 1; off < 64; off <<= 1) {
#pragma unroll
        for (int n = 0; n < Nn; ++n) {
            qnv[0][n] += __shfl_xor(qnv[0][n], off, 64);
            qnv[1][n] += __shfl_xor(qnv[1][n], off, 64);
        }
    }
    // select own item: lanes 0-15 -> bf0 seg gi, lanes 16-31 -> bf1 seg gi
    float qsel0 = qnv[0][0], qsel1 = qnv[1][0];
#pragma unroll
    for (int n = 1; n < Nn; ++n) {
        qsel0 = (gi == n) ? qnv[0][n] : qsel0;
        qsel1 = (gi == n) ? qnv[1][n] : qsel1;
    }
    const float qn_own = pg ? qsel1 : qsel0;

    // --- per-segment projection, one transcendental pass for both bf ---
    const float vn = fsqrtf_(fmaxf(qn_own, EPSF * EPSF));
    const float th = ftanh_pos(vn);
    float s_own = th * frcp(vn);
    float nrm = th;
    if (nrm > MAXNF) { s_own *= MAXNF * frcp(nrm); nrm = MAXNF; }
    const float zn2_own = nrm * nrm;

    // --- neighbor dots for both bf: 26 butterflies interleaved ---
    float rdv[2][Nn - 1];
#pragma unroll
    for (int n = 1; n < Nn; ++n) {
        rdv[0][n - 1] = y00[n - 1] * y00[n] + y01[n - 1] * y01[n];
        rdv[1][n - 1] = y10[n - 1] * y10[n] + y11[n - 1] * y11[n];
    }
#pragma unroll
    for (int off = 1; off < 64; off <<= 1) {
#pragma unroll
        for (int j = 0; j < Nn - 1; ++j) {
            rdv[0][j] += __shfl_xor(rdv[0][j], off, 64);
            rdv[1][j] += __shfl_xor(rdv[1][j], off, 64);
        }
    }
    float rsel0 = rdv[0][0], rsel1 = rdv[1][0];
#pragma unroll
    for (int n = 1; n < Nn - 1; ++n) {
        rsel0 = (gi == n) ? rdv[0][n] : rsel0;
        rsel1 = (gi == n) ? rdv[1][n] : rsel1;
    }
    const float rd_own = pg ? rsel1 : rsel0;

    // --- logmap step j at lane (16p + j), j = 1..13, one pass ---
    const float s_prev   = __shfl(s_own,   lane - 1, 64);
    const float zn2_prev = __shfl(zn2_own, lane - 1, 64);
    const float rd_prev  = __shfl(rd_own,  lane - 1, 64);   // rd[j-1] at lane j

    const float xyv  = -(s_prev * s_own * rd_prev);
    const float x2v  = zn2_prev, yy2 = zn2_own;
    const float c1v  = 1.f + 2.f * xyv + yy2;
    const float c2v  = 1.f - x2v;
    const float rdenv = frcp(fmaxf(1.f + 2.f * xyv + x2v * yy2, EPSF));
    const float un2 = rdenv * rdenv *
        (c1v * c1v * x2v + 2.f * c1v * c2v * xyv + c2v * c2v * yy2);
    const float un  = fsqrtf_(fmaxf(un2, EPSF * EPSF));
    const float lf  = fmaxf(1.f - x2v, EPSF);               // 2/lam
    const float gml = lf * fatanh01(fminf(un, MAXNF)) * frcp(un);
    const float wj  = WNORM * __expf(LN09 * (float)(13 - gi));  // 0.9^(13-j)
    const float gw  = wj * gml * rdenv;
    const float g1_own = -gw * c1v * s_prev;   // contribution to coef[j-1]
    const float g2_own =  gw * c2v * s_own;    // contribution to coef[j]

    // --- v_init for both bf ---
    float vi00 = 0.f, vi01 = 0.f, vi10 = 0.f, vi11 = 0.f;
#pragma unroll
    for (int n = 0; n < Nn; ++n) {
        float cf0 = 0.f, cf1 = 0.f;
        if (n >= 1)      { cf0 = __shfl(g2_own, n, 64);       cf1 = __shfl(g2_own, 16 + n, 64); }
        if (n <= Nn - 2) { cf0 += __shfl(g1_own, n + 1, 64);  cf1 += __shfl(g1_own, 17 + n, 64); }
        vi00 = fmaf(cf0, y00[n], vi00); vi01 = fmaf(cf0, y01[n], vi01);
        vi10 = fmaf(cf1, y10[n], vi10); vi11 = fmaf(cf1, y11[n], vi11);
    }
    const float scl0 = __shfl(s_own, 13, 64),  x2l0 = __shfl(zn2_own, 13, 64);
    const float scl1 = __shfl(s_own, 29, 64),  x2l1 = __shfl(zn2_own, 29, 64);
    const float z000 = y00[Nn-1] * scl0, z010 = y01[Nn-1] * scl0;  // z_last bf0
    const float z100 = y10[Nn-1] * scl1, z110 = y11[Nn-1] * scl1;  // z_last bf1

    // --- logmap0(v_init) -> bcu ---
    float vin20 = vi00 * vi00 + vi01 * vi01;
    float vin21 = vi10 * vi10 + vi11 * vi11;
#pragma unroll
    for (int off = 1; off < 64; off <<= 1) {
        vin20 += __shfl_xor(vin20, off, 64);
        vin21 += __shfl_xor(vin21, off, 64);
    }
    const float vinn0 = fsqrtf_(fmaxf(vin20, EPSF * EPSF));
    const float lgv0  = fatanh01(fminf(vinn0, MAXNF)) * frcp(vinn0);
    const float vinn1 = fsqrtf_(fmaxf(vin21, EPSF * EPSF));
    const float lgv1  = fatanh01(fminf(vinn1, MAXNF)) * frcp(vinn1);
    *reinterpret_cast<float2*>(&bcu[(0 * 4 + c) * Dd + 2 * lane]) =
        make_float2(lgv0 * vi00, lgv0 * vi01);
    *reinterpret_cast<float2*>(&bcu[(4 + c) * Dd + 2 * lane]) =
        make_float2(lgv1 * vi10, lgv1 * vi11);
    __syncthreads();                                            // B3 (xs dead)

    // --- vel matmul: weight loads shared across both bf ---
    float m00 = bv.x, m01 = bv.y, m10 = bv.x, m11 = bv.y;
    {
        const float4* bc40 = reinterpret_cast<const float4*>(bcu + (0 * 4 + c) * Dd);
        const float4* bc41 = reinterpret_cast<const float4*>(bcu + (4 + c) * Dd);
#pragma unroll 4
        for (int kb = 0; kb < Dd / 8; ++kb) {
            float2 w[8];
#pragma unroll
            for (int r = 0; r < 8; ++r)
                w[r] = *reinterpret_cast<const float2*>(Wvp + (8 * kb + r) * Dd);
            const float4 ta0 = bc40[2*kb], tb0 = bc40[2*kb+1];
            const float4 ta1 = bc41[2*kb], tb1 = bc41[2*kb+1];
#define VROW(t0, t1, r) \
            m00 = fmaf(t0, w[r].x, m00); m01 = fmaf(t0, w[r].y, m01); \
            m10 = fmaf(t1, w[r].x, m10); m11 = fmaf(t1, w[r].y, m11);
            VROW(ta0.x, ta1.x, 0) VROW(ta0.y, ta1.y, 1)
            VROW(ta0.z, ta1.z, 2) VROW(ta0.w, ta1.w, 3)
            VROW(tb0.x, tb1.x, 4) VROW(tb0.y, tb1.y, 5)
            VROW(tb0.z, tb1.z, 6) VROW(tb0.w, tb1.w, 7)
#undef VROW
        }
    }
    float mn20 = m00 * m00 + m01 * m01, zdm0 = z000 * m00 + z010 * m01;
    float mn21 = m10 * m10 + m11 * m11, zdm1 = z100 * m10 + z110 * m11;
#pragma unroll
    for (int off = 1; off < 64; off <<= 1) {
        mn20 += __shfl_xor(mn20, off, 64); zdm0 += __shfl_xor(zdm0, off, 64);
        mn21 += __shfl_xor(mn21, off, 64); zdm1 += __shfl_xor(zdm1, off, 64);
    }

    // --- expmap0 of velocity + horizon scalars, lane-parallel over (p, t) ---
    const float sig = frcp(1.f + __expf(-steps[c]));
    {
        const float mn2g = pg ? mn21 : mn20;
        const float zdmg = pg ? zdm1 : zdm0;
        const float x2lg = pg ? x2l1 : x2l0;
        const float mng  = fsqrtf_(fmaxf(mn2g, EPSF * EPSF));
        const float thg  = ftanh_pos(mng);
        float sc2g = thg * frcp(mng);
        float v0ng = thg;
        if (v0ng > MAXNF) { sc2g *= MAXNF * frcp(v0ng); v0ng = MAXNF; }
        const float v0n2g  = mn2g * sc2g * sc2g;
        const float zdotvg = sc2g * zdmg;
        const float lamxg  = 2.f * frcp(fmaxf(1.f - x2lg, EPSF));

        const float alpha = sig * (float)(gi + 1);
        const float vtn2  = alpha * alpha * v0n2g;
        const float vtn   = fsqrtf_(fmaxf(vtn2, EPSF * EPSF));
        const float gg    = ftanh_pos(0.5f * lamxg * vtn);
        const float cyc   = gg * alpha * frcp(vtn);
        const float y2    = cyc * cyc * v0n2g;
        const float xy    = cyc * zdotvg;
        const float c1 = 1.f + 2.f * xy + y2;
        const float c2 = 1.f - x2lg;
        const float rden = frcp(fmaxf(1.f + 2.f * xy + x2lg * y2, EPSF));
        float rn2 = rden * rden *
            (c1 * c1 * x2lg + 2.f * c1 * c2 * xy + c2 * c2 * y2);
        float rn = fsqrtf_(fmaxf(rn2, EPSF * EPSF));
        float sclip = 1.f;
        if (rn > MAXNF) { sclip = MAXNF * frcp(rn); rn = MAXNF; }
        const float At_own = c1 * rden * sclip;         // coeff of z_last
        const float Bt_own = c2 * cyc * rden * sclip;   // coeff of v0t
        if (lane < 32 && gi < Tt) zfns[pg][c][gi] = rn;

        const float sc2_0 = __shfl(sc2g, 0, 64), sc2_1 = __shfl(sc2g, 16, 64);
        const float v0d00 = m00 * sc2_0, v0d01 = m01 * sc2_0;   // v0t bf0
        const float v0d10 = m10 * sc2_1, v0d11 = m11 * sc2_1;   // v0t bf1
#pragma unroll
        for (int t = 0; t < Tt; ++t) {
            const float A0 = __shfl(At_own, t, 64),      B0 = __shfl(Bt_own, t, 64);
            const float A1 = __shfl(At_own, 16 + t, 64), B1 = __shfl(Bt_own, 16 + t, 64);
            *reinterpret_cast<float2*>(ZFL(0, c, t) + 2 * lane) =
                make_float2(fmaf(A0, z000, B0 * v0d00), fmaf(A0, z010, B0 * v0d01));
            *reinterpret_cast<float2*>(ZFL(1, c, t) + 2 * lane) =
                make_float2(fmaf(A1, z100, B1 * v0d10), fmaf(A1, z110, B1 * v0d11));
        }
    }
    __syncthreads();                                            // B4

    // ======= Mobius fusion via Gram matrices: wave wid = horizon t, both bf =======
    {
        float mwa = mobius_w[0], mwb = mobius_w[1], mwc = mobius_w[2], mwd = mobius_w[3];
        const float mx = fmaxf(fmaxf(mwa, mwb), fmaxf(mwc, mwd));
        mwa = __expf(mwa - mx); mwb = __expf(mwb - mx);
        mwc = __expf(mwc - mx); mwd = __expf(mwd - mx);
        const float rse = frcp(mwa + mwb + mwc + mwd);
        const float mw[4] = {mwa * rse, mwb * rse, mwc * rse, mwd * rse};

        const int t = wid;
        float2 e0[4], e1[4];
#pragma unroll
        for (int i = 0; i < 4; ++i) {
            e0[i] = *reinterpret_cast<const float2*>(ZFL(0, i, t) + 2 * lane);
            e1[i] = *reinterpret_cast<const float2*>(ZFL(1, i, t) + 2 * lane);
        }
        float gp[12];
        gp[0]  = e0[0].x*e0[1].x + e0[0].y*e0[1].y;
        gp[1]  = e0[0].x*e0[2].x + e0[0].y*e0[2].y;
        gp[2]  = e0[0].x*e0[3].x + e0[0].y*e0[3].y;
        gp[3]  = e0[1].x*e0[2].x + e0[1].y*e0[2].y;
        gp[4]  = e0[1].x*e0[3].x + e0[1].y*e0[3].y;
        gp[5]  = e0[2].x*e0[3].x + e0[2].y*e0[3].y;
        gp[6]  = e1[0].x*e1[1].x + e1[0].y*e1[1].y;
        gp[7]  = e1[0].x*e1[2].x + e1[0].y*e1[2].y;
        gp[8]  = e1[0].x*e1[3].x + e1[0].y*e1[3].y;
        gp[9]  = e1[1].x*e1[2].x + e1[1].y*e1[2].y;
        gp[10] = e1[1].x*e1[3].x + e1[1].y*e1[3].y;
        gp[11] = e1[2].x*e1[3].x + e1[2].y*e1[3].y;
#pragma unroll
        for (int off = 1; off < 64; off <<= 1) {
#pragma unroll
            for (int k = 0; k < 12; ++k) gp[k] += __shfl_xor(gp[k], off, 64);
        }

        // mob_smul scales: one transcendental pass for 8 (p,i) at lanes 0-3,16-19
        const int il = lane & 3;
        float mwv_own = mw[0];
        mwv_own = (il == 1) ? mw[1] : mwv_own;
        mwv_own = (il == 2) ? mw[2] : mwv_own;
        mwv_own = (il == 3) ? mw[3] : mwv_own;
        const float xn_own = zfns[pg][il][t];
        const float smc = ftanh_pos(mwv_own * fatanh01(xn_own)) * frcp(xn_own);
        float smv[2][4];
#pragma unroll
        for (int i = 0; i < 4; ++i) {
            smv[0][i] = __shfl(smc, i, 64);
            smv[1][i] = __shfl(smc, 16 + i, 64);
        }

#pragma unroll
        for (int p = 0; p < 2; ++p) {
            const float xn0 = zfns[p][0][t], xn1 = zfns[p][1][t];
            const float xn2 = zfns[p][2][t], xn3 = zfns[p][3][t];
            const float Gd[4] = {xn0*xn0, xn1*xn1, xn2*xn2, xn3*xn3};
            const float G[4][4] = {
                {Gd[0], gp[6*p+0], gp[6*p+1], gp[6*p+2]},
                {gp[6*p+0], Gd[1], gp[6*p+3], gp[6*p+4]},
                {gp[6*p+1], gp[6*p+3], Gd[2], gp[6*p+5]},
                {gp[6*p+2], gp[6*p+4], gp[6*p+5], Gd[3]}};
            float a0 = smv[p][0], a1 = 0.f, a2 = 0.f, a3 = 0.f;
            float cn2 = smv[p][0] * smv[p][0] * Gd[0];
#pragma unroll
            for (int i = 1; i < 4; ++i) {
                const float si = smv[p][i];
                const float xy = si * (a0*G[0][i] + a1*G[1][i] + a2*G[2][i] + a3*G[3][i]);
                const float y2 = si * si * Gd[i];
                const float c1 = 1.f + 2.f * xy + y2;
                const float c2 = 1.f - cn2;
                const float rden = frcp(fmaxf(1.f + 2.f * xy + cn2 * y2, EPSF));
                const float f1 = rden * c1, f2 = rden * c2 * si;
                a0 *= f1; a1 *= f1; a2 *= f1; a3 *= f1;
                if (i == 1) a1 += f2; else if (i == 2) a2 += f2; else a3 += f2;
                cn2 = rden * rden * (c1*c1*cn2 + 2.f*c1*c2*xy + c2*c2*y2);
            }
            float cn = fsqrtf_(fmaxf(cn2, EPSF * EPSF));
            float csc = 1.f;
            if (cn > MAXNF) { csc = MAXNF * frcp(cn); cn = MAXNF; }
            const float lg = fatanh01(cn) * frcp(cn) * csc;
            const float ex0 = p ? e1[0].x : e0[0].x, ey0 = p ? e1[0].y : e0[0].y;
            const float ex1 = p ? e1[1].x : e0[1].x, ey1 = p ? e1[1].y : e0[1].y;
            const float ex2 = p ? e1[2].x : e0[2].x, ey2 = p ? e1[2].y : e0[2].y;
            const float ex3 = p ? e1[3].x : e0[3].x, ey3 = p ? e1[3].y : e0[3].y;
            const float u0 = lg * (a0*ex0 + a1*ex1 + a2*ex2 + a3*ex3);
            const float u1 = lg * (a0*ey0 + a1*ey1 + a2*ey2 + a3*ey3);
            *reinterpret_cast<float2*>(&bcu[(p * 4 + t) * Dd + 2 * lane]) =
                make_float2(u0, u1);
        }
    }

    // ---- hinge-loss partials: wave 0, lanes 0-15 bf0, 16-31 bf1 ----
    if (wid == 0) {
        float ddv = 0.f;
        if (lane < 32)
            ddv = 2.f * fatanh01(zfns[pg][lane & 3][gi >> 2]);
        const float ddn = __shfl(ddv, lane + 1, 64);
        float hv = ((lane < 32) && ((lane & 3) != 3))
                 ? fmaxf(ddv - ddn + 0.1f, 0.f) : 0.f;
#pragma unroll
        for (int off = 1; off < 16; off <<= 1) hv += __shfl_xor(hv, off, 64);
        if (lane == 0)  hpart[bf0]     = hv;
        if (lane == 16) hpart[bf0 + 1] = hv;
    }
    __syncthreads();                                            // B5 (zfl dead)

    // ---- reconstruction hidden layer: thread tid = hidden j, 8 accums ----
    {
        const float4* u4 = reinterpret_cast<const float4*>(bcu);
        const float bb = rec_b1[tid];
        float acc[2][4];
#pragma unroll
        for (int p = 0; p < 2; ++p)
#pragma unroll
            for (int t = 0; t < 4; ++t) acc[p][t] = bb;
        const float* w1p = rec_W1 + tid;
#pragma unroll 2
        for (int kb = 0; kb < Dd / 8; ++kb) {
            float wv[8];
#pragma unroll
            for (int r = 0; r < 8; ++r) wv[r] = w1p[(8 * kb + r) * Hh];
#pragma unroll
            for (int r2 = 0; r2 < 2; ++r2) {
#pragma unroll
                for (int p = 0; p < 2; ++p)
#pragma unroll
                    for (int t = 0; t < 4; ++t) {
                        const float4 u = u4[(p * 4 + t) * (Dd / 4) + 2 * kb + r2];
                        acc[p][t] = fmaf(u.x, wv[4*r2+0], acc[p][t]);
                        acc[p][t] = fmaf(u.y, wv[4*r2+1], acc[p][t]);
                        acc[p][t] = fmaf(u.z, wv[4*r2+2], acc[p][t]);
                        acc[p][t] = fmaf(u.w, wv[4*r2+3], acc[p][t]);
                    }
            }
        }
#pragma unroll
        for (int p = 0; p < 2; ++p)
#pragma unroll
            for (int t = 0; t < 4; ++t)
                HB(p, t)[tid] = fmaxf(acc[p][t], 0.f);
    }
    __syncthreads();                                            // B6

    // ---- seg outputs: 96 threads, each handles (t,s) for BOTH bf ----
    if (tid < Tt * SEGc) {
        const int t = tid / SEGc, s = tid - t * SEGc;
        const float4* h40 = reinterpret_cast<const float4*>(HB(0, t));
        const float4* h41 = reinterpret_cast<const float4*>(HB(1, t));
        const float* w2p = rec_W2 + s;
        float acc0 = rec_b2[s], acc1 = acc0;
#pragma unroll 4
        for (int jb = 0; jb < Hh / 8; ++jb) {
            float wv[8];
#pragma unroll
            for (int r = 0; r < 8; ++r) wv[r] = w2p[(8 * jb + r) * SEGc];
            const float4 ha = h40[2*jb], hb = h40[2*jb+1];
            const float4 hc = h41[2*jb], hd = h41[2*jb+1];
            acc0 = fmaf(ha.x, wv[0], acc0); acc0 = fmaf(ha.y, wv[1], acc0);
            acc0 = fmaf(ha.z, wv[2], acc0); acc0 = fmaf(ha.w, wv[3], acc0);
            acc0 = fmaf(hb.x, wv[4], acc0); acc0 = fmaf(hb.y, wv[5], acc0);
            acc0 = fmaf(hb.z, wv[6], acc0); acc0 = fmaf(hb.w, wv[7], acc0);
            acc1 = fmaf(hc.x, wv[0], acc1); acc1 = fmaf(hc.y, wv[1], acc1);
            acc1 = fmaf(hc.z, wv[2], acc1); acc1 = fmaf(hc.w, wv[3], acc1);
            acc1 = fmaf(hd.x, wv[4], acc1); acc1 = fmaf(hd.y, wv[5], acc1);
            acc1 = fmaf(hd.z, wv[6], acc1); acc1 = fmaf(hd.w, wv[7], acc1);
        }
        const float val0 = (acc0 - rb0v) * frcp(rw0v) * stdv0 + mean0;
        const float val1 = (acc1 - rb1v) * frcp(rw1v) * stdv1 + mean1;
        *reinterpret_cast<float2*>(&out[(b * (Tt * SEGc) + tid) * Ff + f0]) =
            make_float2(val0, val1);
    }
#undef XS
#undef ZFL
#undef HB
}

// ---------------- deterministic hloss reduction ----------------
__global__ __launch_bounds__(256) void hloss_kernel(
    const float* __restrict__ hpart, float* __restrict__ out)
{
    __shared__ float sm[256];
    const int tid = threadIdx.x;
    float s = 0.f;
    for (int i = tid; i < BFc; i += 256) s += hpart[i];
    sm[tid] = s;
    __syncthreads();
    for (int off = 128; off > 0; off >>= 1) {
        if (tid < off) sm[tid] += sm[tid + off];
        __syncthreads();
    }
    if (tid == 0) out[Bb * Tt * SEGc * Ff] = sm[0] / (float)(BFc * Tt);
}

extern "C" void kernel_launch(void* const* d_in, const int* in_sizes, int n_in,
                              void* d_out, int out_size, void* d_ws, size_t ws_size,
                              hipStream_t stream) {
    const float* trend   = (const float*)d_in[0];
    const float* scoarse = (const float*)d_in[1];
    const float* sfine   = (const float*)d_in[2];
    const float* resid   = (const float*)d_in[3];
    const float* revin_w = (const float*)d_in[4];
    const float* revin_b = (const float*)d_in[5];
    const float* enc_W   = (const float*)d_in[6];
    const float* enc_b   = (const float*)d_in[7];
    const float* vel_W   = (const float*)d_in[8];
    const float* vel_b   = (const float*)d_in[9];
    const float* steps   = (const float*)d_in[10];
    const float* mobw    = (const float*)d_in[11];
    const float* rec_W1  = (const float*)d_in[12];
    const float* rec_b1  = (const float*)d_in[13];
    const float* rec_W2  = (const float*)d_in[14];
    const float* rec_b2  = (const float*)d_in[15];

    float* out = (float*)d_out;
    float* wsf = (float*)d_ws;           // hpart[8192]

    fused_kernel<<<BFc / 2, 256, 0, stream>>>(
        trend, scoarse, sfine, resid, revin_w, revin_b,
        enc_W, enc_b, vel_W, vel_b, steps, mobw,
        rec_W1, rec_b1, rec_W2, rec_b2,
        out, wsf);
    hloss_kernel<<<1, 256, 0, stream>>>(wsf, out);
}